// Round 9
// baseline (248.125 us; speedup 1.0000x reference)
//
#include <hip/hip_runtime.h>

#define BB 4
#define CC 256
#define HIDD 128
#define NN 4096

typedef short s8v __attribute__((ext_vector_type(8)));
typedef short s4v __attribute__((ext_vector_type(4)));
typedef float f4v __attribute__((ext_vector_type(4)));
typedef unsigned short u16b;

static __device__ __forceinline__ float b2f(unsigned short u) {
    union { unsigned int i; float f; } v; v.i = ((unsigned int)u) << 16; return v.f;
}
static __device__ __forceinline__ unsigned short f2b(float f) {
    union { float f; unsigned int i; } v; v.f = f;
    unsigned int i = v.i;
    return (unsigned short)((i + 0x7fffu + ((i >> 16) & 1u)) >> 16);
}
// fp32 -> bf16 hi + bf16 lo (combined rel err ~2^-18)
static __device__ __forceinline__ void split2(float v, short& hi, short& lo) {
    unsigned short h = f2b(v);
    hi = (short)h;
    lo = (short)f2b(v - b2f(h));
}

// Standard swizzled fragment layout for 16x16x32 MFMA operands.
__device__ __forceinline__ int swz(int k, int rc, int CB) {
    return (((k >> 5) * CB + (rc >> 4)) * 64 + ((k >> 3) & 3) * 16 + (rc & 15)) * 8 + (k & 7);
}
// Permuted swizzle for G': k-slot (q,j) <-> m_local = (j>>2)*16 + q*4 + (j&3).
__device__ __forceinline__ int gswz(int m, int o) {
    int kb = m >> 5, mm = m & 31;
    int qs = (mm >> 2) & 3;
    int js = ((mm >> 4) & 1) * 4 + (mm & 3);
    return ((kb * 8 + (o >> 4)) * 64 + qs * 16 + (o & 15)) * 8 + js;
}

// ---------- Phase 0: weights -> bf16 (theta/phi/mask split hi+lo, g plain) ------
__global__ __launch_bounds__(256) void prep_kernel(
    const float* __restrict__ wt, const float* __restrict__ wp,
    const float* __restrict__ wg, const float* __restrict__ wm,
    u16b* __restrict__ wHb, u16b* __restrict__ wLb, u16b* __restrict__ wgB,
    u16b* __restrict__ wmH, u16b* __restrict__ wmL)
{
    int t = blockIdx.x * 256 + threadIdx.x;   // grid 128 -> 32768 = HID*CC
    short h, l;
    split2(wt[t], h, l); wHb[t] = (u16b)h;           wLb[t] = (u16b)l;
    split2(wp[t], h, l); wHb[32768 + t] = (u16b)h;   wLb[32768 + t] = (u16b)l;
    wgB[t] = f2b(wg[t]);
    split2(wm[t], h, l); wmH[t] = (u16b)h;           wmL[t] = (u16b)l;
}

// ---------- Phase 1: Theta/Phi (split, swizzled) and G (plain, perm-swizzled) ---
__global__ __launch_bounds__(256) void proj_kernel(
    const float* __restrict__ x, const u16b* __restrict__ wHb, const u16b* __restrict__ wLb,
    const u16b* __restrict__ wgB,
    u16b* __restrict__ thetaH, u16b* __restrict__ thetaL,
    u16b* __restrict__ phiH, u16b* __restrict__ phiL, u16b* __restrict__ gB)
{
    int wave = blockIdx.x * 4 + (threadIdx.x >> 6);   // 2048 waves
    int lane = threadIdx.x & 63;
    int l15 = lane & 15, q = lane >> 4;
    int b = wave >> 9;
    int rem = wave & 511;
    int ntile = rem >> 1;
    int half = rem & 1;                                // ot range half*4..half*4+3
    int n0 = ntile << 4;
    const float* xb = x + (size_t)b * CC * NN;

    f4v acc[3][4];
#pragma unroll
    for (int m = 0; m < 3; m++)
#pragma unroll
        for (int i = 0; i < 4; i++) acc[m][i] = (f4v){0.f, 0.f, 0.f, 0.f};

    float xv[8];
    {
        const float* xp = xb + (size_t)(q * 8) * NN + n0 + l15;
#pragma unroll
        for (int j = 0; j < 8; j++) xv[j] = xp[(size_t)j * NN];
    }

    for (int kc = 0; kc < 8; kc++) {
        int c0 = kc * 32;
        float xn[8];
        if (kc < 7) {
            const float* xp = xb + (size_t)(c0 + 32 + q * 8) * NN + n0 + l15;
#pragma unroll
            for (int j = 0; j < 8; j++) xn[j] = xp[(size_t)j * NN];
        }
        s8v bh, bl;
#pragma unroll
        for (int j = 0; j < 8; j++) {
            short h, l;
            split2(xv[j], h, l);
            bh[j] = h; bl[j] = l;
        }
#pragma unroll
        for (int mat = 0; mat < 2; mat++) {
#pragma unroll
            for (int otl = 0; otl < 4; otl++) {
                int ot = half * 4 + otl;
                int woff = mat * 32768 + (ot * 16 + l15) * CC + c0 + q * 8;
                s8v ah = *reinterpret_cast<const s8v*>(wHb + woff);
                s8v al = *reinterpret_cast<const s8v*>(wLb + woff);
                acc[mat][otl] = __builtin_amdgcn_mfma_f32_16x16x32_bf16(ah, bh, acc[mat][otl], 0, 0, 0);
                acc[mat][otl] = __builtin_amdgcn_mfma_f32_16x16x32_bf16(ah, bl, acc[mat][otl], 0, 0, 0);
                acc[mat][otl] = __builtin_amdgcn_mfma_f32_16x16x32_bf16(al, bh, acc[mat][otl], 0, 0, 0);
            }
        }
#pragma unroll
        for (int otl = 0; otl < 4; otl++) {
            int ot = half * 4 + otl;
            const s8v* gw = reinterpret_cast<const s8v*>(wgB + (ot * 16 + l15) * CC + c0 + q * 8);
            acc[2][otl] = __builtin_amdgcn_mfma_f32_16x16x32_bf16(*gw, bh, acc[2][otl], 0, 0, 0);
        }
        if (kc < 7) {
#pragma unroll
            for (int j = 0; j < 8; j++) xv[j] = xn[j];
        }
    }

    size_t boff = (size_t)b * (NN * HIDD);
#pragma unroll
    for (int otl = 0; otl < 4; otl++) {
#pragma unroll
        for (int r = 0; r < 4; r++) {
            int o = (half * 4 + otl) * 16 + q * 4 + r;   // C/D row (hid)
            int n = n0 + l15;                             // C/D col (spatial)
            int offTP = swz(o, n, NN / 16);
            short h, l;
            split2(acc[0][otl][r], h, l);
            thetaH[boff + offTP] = (u16b)h; thetaL[boff + offTP] = (u16b)l;
            split2(acc[1][otl][r], h, l);
            phiH[boff + offTP] = (u16b)h;   phiL[boff + offTP] = (u16b)l;
            gB[boff + gswz(n, o)] = f2b(acc[2][otl][r]);
        }
    }
}

// ---------- small path Phase 2: Lraw[m] = sum_n e^{s[n][m]} ---------------------
__global__ __launch_bounds__(256, 2) void stats_kernel(
    const u16b* __restrict__ thetaH, const u16b* __restrict__ thetaL,
    const u16b* __restrict__ phiH, const u16b* __restrict__ phiL,
    float* __restrict__ Lraw)
{
    int xcd = blockIdx.x & 7;                  // grid 1024
    int inner = blockIdx.x >> 3;               // 0..127
    int b = xcd >> 1;
    int su = (xcd & 1) * 128 + inner;          // 0..255 within batch
    int w = threadIdx.x >> 6;
    int wu = su * 4 + w;                       // 0..1023
    int mg = wu >> 4;                          // 64 groups of 4 mtiles
    int ns = wu & 15;                          // 16-way n-split
    int lane = threadIdx.x & 63;

    size_t boff = (size_t)b * (NN * HIDD);
    const u16b* thH = thetaH + boff; const u16b* thL = thetaL + boff;
    const u16b* phH = phiH + boff;   const u16b* phL = phiL + boff;

    s8v pBh[4][4], pBl[4][4];
#pragma unroll
    for (int mt = 0; mt < 4; mt++)
#pragma unroll
        for (int kb = 0; kb < 4; kb++) {
            int off = ((kb * 256 + (mg * 4 + mt)) * 64 + lane) * 8;
            pBh[mt][kb] = *reinterpret_cast<const s8v*>(phH + off);
            pBl[mt][kb] = *reinterpret_cast<const s8v*>(phL + off);
        }

    float Lp[4];
#pragma unroll
    for (int i = 0; i < 4; i++) Lp[i] = 0.f;

    for (int i = 0; i < 16; i++) {
        int ntile = ns * 16 + i;
        s8v tAh[4], tAl[4];
#pragma unroll
        for (int kb = 0; kb < 4; kb++) {
            int off = ((kb * 256 + ntile) * 64 + lane) * 8;
            tAh[kb] = *reinterpret_cast<const s8v*>(thH + off);
            tAl[kb] = *reinterpret_cast<const s8v*>(thL + off);
        }
#pragma unroll
        for (int mt = 0; mt < 4; mt++) {
            f4v shh = (f4v){0.f, 0.f, 0.f, 0.f};
            f4v sx  = (f4v){0.f, 0.f, 0.f, 0.f};
#pragma unroll
            for (int kb = 0; kb < 4; kb++)
                shh = __builtin_amdgcn_mfma_f32_16x16x32_bf16(tAh[kb], pBh[mt][kb], shh, 0, 0, 0);
#pragma unroll
            for (int kb = 0; kb < 4; kb++) {
                sx = __builtin_amdgcn_mfma_f32_16x16x32_bf16(tAh[kb], pBl[mt][kb], sx, 0, 0, 0);
                sx = __builtin_amdgcn_mfma_f32_16x16x32_bf16(tAl[kb], pBh[mt][kb], sx, 0, 0, 0);
            }
            Lp[mt] += (__expf(shh[0] + sx[0]) + __expf(shh[1] + sx[1]))
                    + (__expf(shh[2] + sx[2]) + __expf(shh[3] + sx[3]));
        }
    }
#pragma unroll
    for (int mt = 0; mt < 4; mt++) {
        float v = Lp[mt];
        v += __shfl_xor(v, 16);
        v += __shfl_xor(v, 32);
        if (lane < 16) atomicAdd(&Lraw[b * NN + (mg * 4 + mt) * 16 + lane], v);
    }
}

// ---------- small path Phase 2b: G'[m,o] = G[m,o] / L[m] ------------------------
__global__ __launch_bounds__(256) void rescale_kernel(
    u16b* __restrict__ gB, const float* __restrict__ Lraw)
{
    int t = blockIdx.x * 256 + threadIdx.x;    // grid 1024
    int flat0 = t * 8;
    int b = flat0 >> 19;
    int rem = flat0 & ((NN * HIDD) - 1);
    int kb = rem >> 12;
    int lane = (rem >> 3) & 63;
    int qs = lane >> 4;
    int mbase = kb * 32 + qs * 4;
    const float* Lp = Lraw + b * NN + mbase;
    u16b* gp = gB + flat0;
    s8v g = *reinterpret_cast<const s8v*>(gp);
    s8v o;
#pragma unroll
    for (int j = 0; j < 8; j++) {
        float v = b2f((unsigned short)g[j]) / Lp[((j >> 2) << 4) + (j & 3)];
        o[j] = (short)f2b(v);
    }
    *reinterpret_cast<s8v*>(gp) = o;
}

// ---------- small path Phase 3: Out += softmax(S) @ G', fused S^T recompute -----
__global__ __launch_bounds__(256, 2) void attn_kernel(
    const u16b* __restrict__ thetaH, const u16b* __restrict__ thetaL,
    const u16b* __restrict__ phiH, const u16b* __restrict__ phiL,
    const u16b* __restrict__ gB, float* __restrict__ outAcc)
{
    int xcd = blockIdx.x & 7;                  // grid 1024
    int inner = blockIdx.x >> 3;               // 0..127
    int combo = xcd * 4 + (inner & 3);         // 0..31 = b*8+ms (XCD-pinned)
    int b = combo >> 3;
    int ms = combo & 7;                        // 8-way m-split
    int ng = inner >> 2;                       // 0..31
    int w = threadIdx.x >> 6;
    int lane = threadIdx.x & 63;
    int l15 = lane & 15, q = lane >> 4;
    int ntile0 = ng * 8 + w * 2;

    size_t boff = (size_t)b * (NN * HIDD);
    const u16b* thH = thetaH + boff; const u16b* thL = thetaL + boff;
    const u16b* phH = phiH + boff;   const u16b* phL = phiL + boff;
    const u16b* gp = gB + boff;

    s8v tBh[2][4], tBl[2][4];
#pragma unroll
    for (int nt = 0; nt < 2; nt++)
#pragma unroll
        for (int kb = 0; kb < 4; kb++) {
            int off = ((kb * 256 + ntile0 + nt) * 64 + lane) * 8;
            tBh[nt][kb] = *reinterpret_cast<const s8v*>(thH + off);
            tBl[nt][kb] = *reinterpret_cast<const s8v*>(thL + off);
        }

    f4v acc[2][8];
#pragma unroll
    for (int nt = 0; nt < 2; nt++)
#pragma unroll
        for (int i = 0; i < 8; i++) acc[nt][i] = (f4v){0.f, 0.f, 0.f, 0.f};

    for (int mt = 0; mt < 16; mt++) {
        int m0 = ms * 512 + mt * 32;
        s8v pf[2];
#pragma unroll
        for (int h = 0; h < 2; h++) {
            int mtile = (m0 >> 4) + h;
            s8v pAh[4], pAl[4];
#pragma unroll
            for (int kb = 0; kb < 4; kb++) {
                int off = ((kb * 256 + mtile) * 64 + lane) * 8;
                pAh[kb] = *reinterpret_cast<const s8v*>(phH + off);
                pAl[kb] = *reinterpret_cast<const s8v*>(phL + off);
            }
#pragma unroll
            for (int nt = 0; nt < 2; nt++) {
                f4v shh = (f4v){0.f, 0.f, 0.f, 0.f};
                f4v sx  = (f4v){0.f, 0.f, 0.f, 0.f};
#pragma unroll
                for (int kb = 0; kb < 4; kb++)
                    shh = __builtin_amdgcn_mfma_f32_16x16x32_bf16(pAh[kb], tBh[nt][kb], shh, 0, 0, 0);
#pragma unroll
                for (int kb = 0; kb < 4; kb++) {
                    sx = __builtin_amdgcn_mfma_f32_16x16x32_bf16(pAh[kb], tBl[nt][kb], sx, 0, 0, 0);
                    sx = __builtin_amdgcn_mfma_f32_16x16x32_bf16(pAl[kb], tBh[nt][kb], sx, 0, 0, 0);
                }
#pragma unroll
                for (int r = 0; r < 4; r++)
                    pf[nt][h * 4 + r] = (short)f2b(__expf(shh[r] + sx[r]));
            }
        }
        int kb2 = m0 >> 5;
#pragma unroll
        for (int ot = 0; ot < 8; ot++) {
            s8v gf = *reinterpret_cast<const s8v*>(gp + ((kb2 * 8 + ot) * 64 + lane) * 8);
#pragma unroll
            for (int nt = 0; nt < 2; nt++)
                acc[nt][ot] = __builtin_amdgcn_mfma_f32_16x16x32_bf16(pf[nt], gf, acc[nt][ot], 0, 0, 0);
        }
    }

    float* oa = outAcc + (size_t)b * (NN * HIDD);
#pragma unroll
    for (int nt = 0; nt < 2; nt++) {
        int n_base = (ntile0 + nt) * 16;
#pragma unroll
        for (int ot = 0; ot < 8; ot++) {
#pragma unroll
            for (int r = 0; r < 4; r++) {
                int n = n_base + q * 4 + r;
                int o = ot * 16 + l15;
                atomicAdd(&oa[swz(o, n, NN / 16)], acc[nt][ot][r]);
            }
        }
    }
}

// ---------- big path Phase 2: S-pass, software-pipelined ------------------------
// 16 per-mtile iterations, depth-1 phi prefetch, P stored as two 8B halves.
// L via per-wave LDS rows -> private per-block Lpart slice (no atomics).
__global__ __launch_bounds__(256, 2) void spass_kernel(
    const u16b* __restrict__ thetaH, const u16b* __restrict__ thetaL,
    const u16b* __restrict__ phiH, const u16b* __restrict__ phiL,
    u16b* __restrict__ P, float* __restrict__ Lpart)
{
    int xcd = blockIdx.x & 7;                  // grid 2048
    int inner = blockIdx.x >> 3;               // 0..255
    int combo = xcd * 8 + (inner & 7);         // 0..63 = b*16+ms
    int b = combo >> 4;
    int ms = combo & 15;                       // 16-way m-split
    int ng = inner >> 3;                       // 0..31
    int w = threadIdx.x >> 6;
    int lane = threadIdx.x & 63;
    int l15 = lane & 15, q = lane >> 4;
    int ntile0 = ng * 8 + w * 2;

    size_t boff = (size_t)b * (NN * HIDD);
    const u16b* thH = thetaH + boff; const u16b* thL = thetaL + boff;
    const u16b* phH = phiH + boff;   const u16b* phL = phiL + boff;
    u16b* Pb = P + (size_t)b * NN * NN;

    __shared__ float Lacc[4][256];             // [wave][m_local], each written once

    s8v tBh[2][4], tBl[2][4];
#pragma unroll
    for (int nt = 0; nt < 2; nt++)
#pragma unroll
        for (int kb = 0; kb < 4; kb++) {
            int off = ((kb * 256 + ntile0 + nt) * 64 + lane) * 8;
            tBh[nt][kb] = *reinterpret_cast<const s8v*>(thH + off);
            tBl[nt][kb] = *reinterpret_cast<const s8v*>(thL + off);
        }

    int ph = ng & 15;                          // stagger phase
    s8v pAh[4], pAl[4];
    {
        int mtile = ms * 16 + ph;
#pragma unroll
        for (int kb = 0; kb < 4; kb++) {
            int off = ((kb * 256 + mtile) * 64 + lane) * 8;
            pAh[kb] = *reinterpret_cast<const s8v*>(phH + off);
            pAl[kb] = *reinterpret_cast<const s8v*>(phL + off);
        }
    }

    for (int i = 0; i < 16; i++) {
        int mtr  = (i + ph) & 15;
        int mtrn = (i + 1 + ph) & 15;
        // prefetch next mtile's phi fragments (wraps harmlessly on last iter)
        s8v pAhN[4], pAlN[4];
        {
            int mtilen = ms * 16 + mtrn;
#pragma unroll
            for (int kb = 0; kb < 4; kb++) {
                int off = ((kb * 256 + mtilen) * 64 + lane) * 8;
                pAhN[kb] = *reinterpret_cast<const s8v*>(phH + off);
                pAlN[kb] = *reinterpret_cast<const s8v*>(phL + off);
            }
        }
        // S^T tile for both ntiles (split-bf16, 12 MFMA each, interleaved)
        f4v s0h = (f4v){0.f, 0.f, 0.f, 0.f};
        f4v s1h = (f4v){0.f, 0.f, 0.f, 0.f};
        f4v s0x = (f4v){0.f, 0.f, 0.f, 0.f};
        f4v s1x = (f4v){0.f, 0.f, 0.f, 0.f};
#pragma unroll
        for (int kb = 0; kb < 4; kb++) {
            s0h = __builtin_amdgcn_mfma_f32_16x16x32_bf16(pAh[kb], tBh[0][kb], s0h, 0, 0, 0);
            s1h = __builtin_amdgcn_mfma_f32_16x16x32_bf16(pAh[kb], tBh[1][kb], s1h, 0, 0, 0);
        }
#pragma unroll
        for (int kb = 0; kb < 4; kb++) {
            s0x = __builtin_amdgcn_mfma_f32_16x16x32_bf16(pAh[kb], tBl[0][kb], s0x, 0, 0, 0);
            s1x = __builtin_amdgcn_mfma_f32_16x16x32_bf16(pAh[kb], tBl[1][kb], s1x, 0, 0, 0);
            s0x = __builtin_amdgcn_mfma_f32_16x16x32_bf16(pAl[kb], tBh[0][kb], s0x, 0, 0, 0);
            s1x = __builtin_amdgcn_mfma_f32_16x16x32_bf16(pAl[kb], tBh[1][kb], s1x, 0, 0, 0);
        }
        float ev[2][4];
#pragma unroll
        for (int r = 0; r < 4; r++) {
            ev[0][r] = __expf(s0h[r] + s0x[r]);
            ev[1][r] = __expf(s1h[r] + s1x[r]);
        }
        // store P half-fragments: h selects k-slots 0..3 / 4..7
        int mtile = ms * 16 + mtr;
        int kb2 = mtile >> 1;
        int h = mtile & 1;
#pragma unroll
        for (int nt = 0; nt < 2; nt++) {
            s4v pf;
#pragma unroll
            for (int r = 0; r < 4; r++) pf[r] = (short)f2b(ev[nt][r]);
            *reinterpret_cast<s4v*>(
                Pb + ((size_t)(kb2 * 256 + ntile0 + nt) * 64 + lane) * 8 + h * 4) = pf;
        }
        // column-sum over this wave's 32 n (2 nt x 16 l15-lanes)
        float cs[4];
#pragma unroll
        for (int r = 0; r < 4; r++) {
            cs[r] = ev[0][r] + ev[1][r];
            cs[r] += __shfl_xor(cs[r], 1);
            cs[r] += __shfl_xor(cs[r], 2);
            cs[r] += __shfl_xor(cs[r], 4);
            cs[r] += __shfl_xor(cs[r], 8);
        }
        if (l15 == 0) {
#pragma unroll
            for (int r = 0; r < 4; r++)
                Lacc[w][mtr * 16 + q * 4 + r] = cs[r];
        }
        // rotate prefetch registers
#pragma unroll
        for (int kb = 0; kb < 4; kb++) { pAh[kb] = pAhN[kb]; pAl[kb] = pAlN[kb]; }
    }
    __syncthreads();
    {
        int t = threadIdx.x;                   // 0..255 == m_local
        float s = (Lacc[0][t] + Lacc[1][t]) + (Lacc[2][t] + Lacc[3][t]);
        Lpart[((size_t)(combo * 32 + ng)) * 256 + t] = s;
    }
}

// ---------- big path Phase 2b: fused L-sum + G rescale --------------------------
// Each block: sum its kb's 32 L values from the 32 Lpart slices (LDS), then
// rescale its 2048 G' elements. Replaces lsum + rescale.
__global__ __launch_bounds__(256) void lrescale_kernel(
    u16b* __restrict__ gB, const float* __restrict__ Lpart)
{
    int t = blockIdx.x;                        // grid 1024
    int b = t >> 8;
    int kb = (t & 255) >> 1;                   // m>>5, 0..127
    int combo = b * 16 + (kb >> 3);
    int mlbase = (kb & 7) * 32;
    __shared__ float sLp[32][9];
    __shared__ float sL[32];
    int ti = threadIdx.x;
    {
        int mi = ti & 31;                      // = qs*8 + h*4 + r
        int ngp = ti >> 5;                     // 0..7
        int qs = mi >> 3, h = (mi >> 2) & 1, r = mi & 3;
        int ml = mlbase + qs * 4 + h * 16 + r;
        const float* base = Lpart + ((size_t)(combo * 32 + ngp * 4)) * 256 + ml;
        sLp[mi][ngp] = (base[0] + base[256]) + (base[512] + base[768]);
    }
    __syncthreads();
    if (ti < 32) {
        float s = 0.f;
#pragma unroll
        for (int k = 0; k < 8; k++) s += sLp[ti][k];
        sL[ti] = s;
    }
    __syncthreads();
    size_t flat0 = (size_t)b * (NN * HIDD) + (size_t)(t & 255) * 2048 + (size_t)ti * 8;
    int lane = ti & 63;                        // ((t&255)*2048 + ti*8)>>3 mod 64 == ti mod 64
    int qs = lane >> 4;
    u16b* gp = gB + flat0;
    s8v g = *reinterpret_cast<const s8v*>(gp);
    s8v o;
#pragma unroll
    for (int j = 0; j < 8; j++) {
        int mi = qs * 8 + ((j >> 2) << 2) + (j & 3);
        float v = b2f((unsigned short)g[j]) / sL[mi];
        o[j] = (short)f2b(v);
    }
    *reinterpret_cast<s8v*>(gp) = o;
}

// ---------- big path Phase 3: partial[ms] = P-slice @ G' (NO atomics) -----------
__global__ __launch_bounds__(256, 4) void pv_kernel(
    const u16b* __restrict__ P, const u16b* __restrict__ gB, u16b* __restrict__ pvPart)
{
    int xcd = blockIdx.x & 7;                  // grid 1024
    int inner = blockIdx.x >> 3;               // 0..127
    int combo = xcd * 2 + (inner & 1);         // 0..15 = b*4+ms (XCD-pinned)
    int b = combo >> 2;
    int ms = combo & 3;                        // 4-way m-split
    int ng = inner >> 1;                       // 0..63
    int w = threadIdx.x >> 6;
    int lane = threadIdx.x & 63;
    int l15 = lane & 15, q = lane >> 4;
    int ntile = ng * 4 + w;                    // 0..255, one ntile per wave

    const u16b* Pb = P + (size_t)b * NN * NN;
    const u16b* gp = gB + (size_t)b * (NN * HIDD);

    f4v acc[8];
#pragma unroll
    for (int i = 0; i < 8; i++) acc[i] = (f4v){0.f, 0.f, 0.f, 0.f};

    int ph = ng & 31;                          // stagger phase
    int k0 = ms * 32 + ph;
    int k1 = ms * 32 + ((ph + 1) & 31);
    s8v pcur = *reinterpret_cast<const s8v*>(Pb + ((size_t)(k0 * 256 + ntile) * 64 + lane) * 8);
    s8v pnx1 = *reinterpret_cast<const s8v*>(Pb + ((size_t)(k1 * 256 + ntile) * 64 + lane) * 8);

    for (int it = 0; it < 32; it++) {
        int kb2  = ms * 32 + ((it + ph) & 31);
        int kb2n = ms * 32 + ((it + 2 + ph) & 31);
        s8v pnx2 = *reinterpret_cast<const s8v*>(Pb + ((size_t)(kb2n * 256 + ntile) * 64 + lane) * 8);
#pragma unroll
        for (int ot = 0; ot < 8; ot++) {
            s8v gf = *reinterpret_cast<const s8v*>(gp + ((kb2 * 8 + ot) * 64 + lane) * 8);
            acc[ot] = __builtin_amdgcn_mfma_f32_16x16x32_bf16(pcur, gf, acc[ot], 0, 0, 0);
        }
        pcur = pnx1;
        pnx1 = pnx2;
    }

    u16b* pp = pvPart + (size_t)ms * ((size_t)BB * NN * HIDD) + (size_t)b * (NN * HIDD);
    int n_base = ntile * 16;
#pragma unroll
    for (int ot = 0; ot < 8; ot++) {
#pragma unroll
        for (int r = 0; r < 4; r++) {
            int n = n_base + q * 4 + r;
            int o = ot * 16 + l15;
            pp[swz(o, n, NN / 16)] = f2b(acc[ot][r]);
        }
    }
}

// ---------- big path Phase 4: y = x + w_mask @ (sum of partials)^T --------------
__global__ __launch_bounds__(256) void final_big_kernel(
    const float* __restrict__ x, const u16b* __restrict__ wmH, const u16b* __restrict__ wmL,
    const u16b* __restrict__ pvPart, float* __restrict__ y)
{
    int wave = blockIdx.x * 4 + (threadIdx.x >> 6);   // 4096 waves
    int lane = threadIdx.x & 63;
    int l15 = lane & 15, q = lane >> 4;
    int b = wave >> 10;
    int rem = wave & 1023;
    int ctile = rem >> 6;
    int n64 = rem & 63;
    const size_t pstride = (size_t)BB * NN * HIDD;
    const u16b* pb = pvPart + (size_t)b * (NN * HIDD);
    const float* xb = x + (size_t)b * CC * NN;
    float* yb = y + (size_t)b * CC * NN;
    int c0 = ctile * 16;

    s8v aH[4], aL[4];
#pragma unroll
    for (int kb = 0; kb < 4; kb++) {
        int off = (c0 + l15) * HIDD + kb * 32 + q * 8;
        aH[kb] = *reinterpret_cast<const s8v*>(wmH + off);
        aL[kb] = *reinterpret_cast<const s8v*>(wmL + off);
    }

#pragma unroll
    for (int nt = 0; nt < 4; nt++) {
        int ntile = n64 * 4 + nt;
        f4v acc = (f4v){0.f, 0.f, 0.f, 0.f};
#pragma unroll
        for (int kb = 0; kb < 4; kb++) {
            size_t fo = ((size_t)(kb * 256 + ntile) * 64 + lane) * 8;
            float s[8];
#pragma unroll
            for (int j = 0; j < 8; j++) s[j] = 0.f;
#pragma unroll
            for (int p = 0; p < 4; p++) {
                s8v v = *reinterpret_cast<const s8v*>(pb + p * pstride + fo);
#pragma unroll
                for (int j = 0; j < 8; j++) s[j] += b2f((unsigned short)v[j]);
            }
            s8v bhv, blv;
#pragma unroll
            for (int j = 0; j < 8; j++) {
                short h, l;
                split2(s[j], h, l);
                bhv[j] = h; blv[j] = l;
            }
            acc = __builtin_amdgcn_mfma_f32_16x16x32_bf16(aH[kb], bhv, acc, 0, 0, 0);
            acc = __builtin_amdgcn_mfma_f32_16x16x32_bf16(aH[kb], blv, acc, 0, 0, 0);
            acc = __builtin_amdgcn_mfma_f32_16x16x32_bf16(aL[kb], bhv, acc, 0, 0, 0);
        }
#pragma unroll
        for (int r = 0; r < 4; r++) {
            int c = c0 + q * 4 + r;
            int n = ntile * 16 + l15;
            size_t idx = (size_t)c * NN + n;
            yb[idx] = xb[idx] + acc[r];
        }
    }
}

// ---------- small path Phase 4: y = x + w_mask @ Out^T --------------------------
__global__ __launch_bounds__(256) void final_kernel(
    const float* __restrict__ x, const u16b* __restrict__ wmH, const u16b* __restrict__ wmL,
    const float* __restrict__ outAcc, float* __restrict__ y)
{
    int wave = blockIdx.x * 4 + (threadIdx.x >> 6);   // 4096 waves
    int lane = threadIdx.x & 63;
    int l15 = lane & 15, q = lane >> 4;
    int b = wave >> 10;
    int rem = wave & 1023;
    int ctile = rem >> 6;
    int n64 = rem & 63;
    const float* oa = outAcc + (size_t)b * (NN * HIDD);
    const float* xb = x + (size_t)b * CC * NN;
    float* yb = y + (size_t)b * CC * NN;
    int c0 = ctile * 16;

    s8v aH[4], aL[4];
#pragma unroll
    for (int kb = 0; kb < 4; kb++) {
        int off = (c0 + l15) * HIDD + kb * 32 + q * 8;
        aH[kb] = *reinterpret_cast<const s8v*>(wmH + off);
        aL[kb] = *reinterpret_cast<const s8v*>(wmL + off);
    }

#pragma unroll
    for (int nt = 0; nt < 4; nt++) {
        int ntile = n64 * 4 + nt;
        f4v acc = (f4v){0.f, 0.f, 0.f, 0.f};
#pragma unroll
        for (int kb = 0; kb < 4; kb++) {
            const float* bp = oa + ((size_t)(kb * 256 + ntile) * 64 + lane) * 8;
            f4v b0 = *reinterpret_cast<const f4v*>(bp);
            f4v b1 = *reinterpret_cast<const f4v*>(bp + 4);
            s8v bhv, blv;
#pragma unroll
            for (int j = 0; j < 4; j++) {
                short h, l;
                split2(b0[j], h, l); bhv[j] = h; blv[j] = l;
                split2(b1[j], h, l); bhv[j + 4] = h; blv[j + 4] = l;
            }
            acc = __builtin_amdgcn_mfma_f32_16x16x32_bf16(aH[kb], bhv, acc, 0, 0, 0);
            acc = __builtin_amdgcn_mfma_f32_16x16x32_bf16(aH[kb], blv, acc, 0, 0, 0);
            acc = __builtin_amdgcn_mfma_f32_16x16x32_bf16(aL[kb], bhv, acc, 0, 0, 0);
        }
#pragma unroll
        for (int r = 0; r < 4; r++) {
            int c = c0 + q * 4 + r;
            int n = ntile * 16 + l15;
            size_t idx = (size_t)c * NN + n;
            yb[idx] = xb[idx] + acc[r];
        }
    }
}

extern "C" void kernel_launch(void* const* d_in, const int* in_sizes, int n_in,
                              void* d_out, int out_size, void* d_ws, size_t ws_size,
                              hipStream_t stream)
{
    (void)in_sizes; (void)n_in; (void)out_size;
    const float* x  = (const float*)d_in[0];
    const float* wt = (const float*)d_in[1];
    const float* wp = (const float*)d_in[2];
    const float* wg = (const float*)d_in[3];
    const float* wm = (const float*)d_in[4];
    float* y = (float*)d_out;

    char* ws = (char*)d_ws;
    const size_t MB = 1 << 20;
    u16b* thetaH = (u16b*)(ws + 0 * MB);
    u16b* thetaL = (u16b*)(ws + 4 * MB);
    u16b* phiH   = (u16b*)(ws + 8 * MB);
    u16b* phiL   = (u16b*)(ws + 12 * MB);
    u16b* pvPart = (u16b*)(ws + 0 * MB);                   // 16 MB, overlays theta/phi
    u16b* gB     = (u16b*)(ws + 16 * MB);
    float* outAcc = (float*)(ws + 20 * MB);                // 8 MB fp32 (small path)
    float* Lraw   = (float*)(ws + 28 * MB);                // 64 KB (small path)
    char* wbase = ws + 28 * MB + (64 << 10);
    u16b* wHb = (u16b*)(wbase);                            // 128 KB
    u16b* wLb = (u16b*)(wbase + (128 << 10));              // 128 KB
    u16b* wgB = (u16b*)(wbase + (256 << 10));              // 64 KB
    u16b* wmH = (u16b*)(wbase + (320 << 10));              // 64 KB
    u16b* wmL = (u16b*)(wbase + (384 << 10));              // 64 KB
    float* Lpart = (float*)(ws + 30 * MB);                 // 2 MB (big path)
    u16b* P   = (u16b*)(ws + 32 * MB);                     // 134.2 MB (big path)

    const size_t need_big = 32 * MB + (size_t)BB * NN * NN * sizeof(u16b);
    const bool big = ws_size >= need_big;

    hipLaunchKernelGGL(prep_kernel, dim3(128), dim3(256), 0, stream,
                       wt, wp, wg, wm, wHb, wLb, wgB, wmH, wmL);
    hipLaunchKernelGGL(proj_kernel, dim3(512), dim3(256), 0, stream,
                       x, wHb, wLb, wgB, thetaH, thetaL, phiH, phiL, gB);

    if (big) {
        hipLaunchKernelGGL(spass_kernel,    dim3(2048), dim3(256), 0, stream,
                           thetaH, thetaL, phiH, phiL, P, Lpart);
        hipLaunchKernelGGL(lrescale_kernel, dim3(1024), dim3(256), 0, stream, gB, Lpart);
        // pv overwrites the theta/phi region (dead after spass) with bf16 partials
        hipLaunchKernelGGL(pv_kernel,       dim3(1024), dim3(256), 0, stream, P, gB, pvPart);
        hipLaunchKernelGGL(final_big_kernel, dim3(1024), dim3(256), 0, stream,
                           x, wmH, wmL, pvPart, y);
    } else {
        hipMemsetAsync(Lraw, 0, (size_t)BB * NN * sizeof(float), stream);
        hipMemsetAsync(outAcc, 0, (size_t)BB * NN * HIDD * sizeof(float), stream);
        hipLaunchKernelGGL(stats_kernel,   dim3(1024), dim3(256), 0, stream,
                           thetaH, thetaL, phiH, phiL, Lraw);
        hipLaunchKernelGGL(rescale_kernel, dim3(1024), dim3(256), 0, stream, gB, Lraw);
        hipLaunchKernelGGL(attn_kernel,    dim3(1024), dim3(256), 0, stream,
                           thetaH, thetaL, phiH, phiL, gB, outAcc);
        hipLaunchKernelGGL(final_kernel,   dim3(1024), dim3(256), 0, stream,
                           x, wmH, wmL, outAcc, y);
    }
}

// Round 10
// 243.589 us; speedup vs baseline: 1.0186x; 1.0186x over previous
//
#include <hip/hip_runtime.h>

#define BB 4
#define CC 256
#define HIDD 128
#define NN 4096

typedef short s8v __attribute__((ext_vector_type(8)));
typedef float f4v __attribute__((ext_vector_type(4)));
typedef unsigned short u16b;

static __device__ __forceinline__ float b2f(unsigned short u) {
    union { unsigned int i; float f; } v; v.i = ((unsigned int)u) << 16; return v.f;
}
static __device__ __forceinline__ unsigned short f2b(float f) {
    union { float f; unsigned int i; } v; v.f = f;
    unsigned int i = v.i;
    return (unsigned short)((i + 0x7fffu + ((i >> 16) & 1u)) >> 16);
}
// fp32 -> bf16 hi + bf16 lo (combined rel err ~2^-18)
static __device__ __forceinline__ void split2(float v, short& hi, short& lo) {
    unsigned short h = f2b(v);
    hi = (short)h;
    lo = (short)f2b(v - b2f(h));
}

// Standard swizzled fragment layout for 16x16x32 MFMA operands.
__device__ __forceinline__ int swz(int k, int rc, int CB) {
    return (((k >> 5) * CB + (rc >> 4)) * 64 + ((k >> 3) & 3) * 16 + (rc & 15)) * 8 + (k & 7);
}
// Permuted swizzle for G': k-slot (q,j) <-> m_local = (j>>2)*16 + q*4 + (j&3).
__device__ __forceinline__ int gswz(int m, int o) {
    int kb = m >> 5, mm = m & 31;
    int qs = (mm >> 2) & 3;
    int js = ((mm >> 4) & 1) * 4 + (mm & 3);
    return ((kb * 8 + (o >> 4)) * 64 + qs * 16 + (o & 15)) * 8 + js;
}

// ---------- Phase 0: weights -> bf16 (theta/phi split hi+lo, g/mask plain) ------
__global__ __launch_bounds__(256) void prep_kernel(
    const float* __restrict__ wt, const float* __restrict__ wp,
    const float* __restrict__ wg, const float* __restrict__ wm,
    u16b* __restrict__ wHb, u16b* __restrict__ wLb, u16b* __restrict__ wgB,
    u16b* __restrict__ wmH, u16b* __restrict__ wmL)
{
    int t = blockIdx.x * 256 + threadIdx.x;   // grid 128 -> 32768 = HID*CC
    short h, l;
    split2(wt[t], h, l); wHb[t] = (u16b)h;           wLb[t] = (u16b)l;
    split2(wp[t], h, l); wHb[32768 + t] = (u16b)h;   wLb[32768 + t] = (u16b)l;
    wgB[t] = f2b(wg[t]);
    split2(wm[t], h, l); wmH[t] = (u16b)h;           wmL[t] = (u16b)l;
}

// ---------- Phase 1: Theta/Phi (split, swizzled) and G (plain, perm-swizzled) ---
__global__ __launch_bounds__(256) void proj_kernel(
    const float* __restrict__ x, const u16b* __restrict__ wHb, const u16b* __restrict__ wLb,
    const u16b* __restrict__ wgB,
    u16b* __restrict__ thetaH, u16b* __restrict__ thetaL,
    u16b* __restrict__ phiH, u16b* __restrict__ phiL, u16b* __restrict__ gB)
{
    int wave = blockIdx.x * 4 + (threadIdx.x >> 6);   // 2048 waves
    int lane = threadIdx.x & 63;
    int l15 = lane & 15, q = lane >> 4;
    int b = wave >> 9;
    int rem = wave & 511;
    int ntile = rem >> 1;
    int half = rem & 1;                                // ot range half*4..half*4+3
    int n0 = ntile << 4;
    const float* xb = x + (size_t)b * CC * NN;

    f4v acc[3][4];
#pragma unroll
    for (int m = 0; m < 3; m++)
#pragma unroll
        for (int i = 0; i < 4; i++) acc[m][i] = (f4v){0.f, 0.f, 0.f, 0.f};

    float xv[8];
    {
        const float* xp = xb + (size_t)(q * 8) * NN + n0 + l15;
#pragma unroll
        for (int j = 0; j < 8; j++) xv[j] = xp[(size_t)j * NN];
    }

    for (int kc = 0; kc < 8; kc++) {
        int c0 = kc * 32;
        float xn[8];
        if (kc < 7) {
            const float* xp = xb + (size_t)(c0 + 32 + q * 8) * NN + n0 + l15;
#pragma unroll
            for (int j = 0; j < 8; j++) xn[j] = xp[(size_t)j * NN];
        }
        s8v bh, bl;
#pragma unroll
        for (int j = 0; j < 8; j++) {
            short h, l;
            split2(xv[j], h, l);
            bh[j] = h; bl[j] = l;
        }
#pragma unroll
        for (int mat = 0; mat < 2; mat++) {
#pragma unroll
            for (int otl = 0; otl < 4; otl++) {
                int ot = half * 4 + otl;
                int woff = mat * 32768 + (ot * 16 + l15) * CC + c0 + q * 8;
                s8v ah = *reinterpret_cast<const s8v*>(wHb + woff);
                s8v al = *reinterpret_cast<const s8v*>(wLb + woff);
                acc[mat][otl] = __builtin_amdgcn_mfma_f32_16x16x32_bf16(ah, bh, acc[mat][otl], 0, 0, 0);
                acc[mat][otl] = __builtin_amdgcn_mfma_f32_16x16x32_bf16(ah, bl, acc[mat][otl], 0, 0, 0);
                acc[mat][otl] = __builtin_amdgcn_mfma_f32_16x16x32_bf16(al, bh, acc[mat][otl], 0, 0, 0);
            }
        }
#pragma unroll
        for (int otl = 0; otl < 4; otl++) {
            int ot = half * 4 + otl;
            const s8v* gw = reinterpret_cast<const s8v*>(wgB + (ot * 16 + l15) * CC + c0 + q * 8);
            acc[2][otl] = __builtin_amdgcn_mfma_f32_16x16x32_bf16(*gw, bh, acc[2][otl], 0, 0, 0);
        }
        if (kc < 7) {
#pragma unroll
            for (int j = 0; j < 8; j++) xv[j] = xn[j];
        }
    }

    size_t boff = (size_t)b * (NN * HIDD);
#pragma unroll
    for (int otl = 0; otl < 4; otl++) {
#pragma unroll
        for (int r = 0; r < 4; r++) {
            int o = (half * 4 + otl) * 16 + q * 4 + r;   // C/D row (hid)
            int n = n0 + l15;                             // C/D col (spatial)
            int offTP = swz(o, n, NN / 16);
            short h, l;
            split2(acc[0][otl][r], h, l);
            thetaH[boff + offTP] = (u16b)h; thetaL[boff + offTP] = (u16b)l;
            split2(acc[1][otl][r], h, l);
            phiH[boff + offTP] = (u16b)h;   phiL[boff + offTP] = (u16b)l;
            gB[boff + gswz(n, o)] = f2b(acc[2][otl][r]);
        }
    }
}

// ---------- small path Phase 2: Lraw[m] = sum_n e^{s[n][m]} ---------------------
__global__ __launch_bounds__(256, 2) void stats_kernel(
    const u16b* __restrict__ thetaH, const u16b* __restrict__ thetaL,
    const u16b* __restrict__ phiH, const u16b* __restrict__ phiL,
    float* __restrict__ Lraw)
{
    int xcd = blockIdx.x & 7;                  // grid 1024
    int inner = blockIdx.x >> 3;               // 0..127
    int b = xcd >> 1;
    int su = (xcd & 1) * 128 + inner;          // 0..255 within batch
    int w = threadIdx.x >> 6;
    int wu = su * 4 + w;                       // 0..1023
    int mg = wu >> 4;                          // 64 groups of 4 mtiles
    int ns = wu & 15;                          // 16-way n-split
    int lane = threadIdx.x & 63;

    size_t boff = (size_t)b * (NN * HIDD);
    const u16b* thH = thetaH + boff; const u16b* thL = thetaL + boff;
    const u16b* phH = phiH + boff;   const u16b* phL = phiL + boff;

    s8v pBh[4][4], pBl[4][4];
#pragma unroll
    for (int mt = 0; mt < 4; mt++)
#pragma unroll
        for (int kb = 0; kb < 4; kb++) {
            int off = ((kb * 256 + (mg * 4 + mt)) * 64 + lane) * 8;
            pBh[mt][kb] = *reinterpret_cast<const s8v*>(phH + off);
            pBl[mt][kb] = *reinterpret_cast<const s8v*>(phL + off);
        }

    float Lp[4];
#pragma unroll
    for (int i = 0; i < 4; i++) Lp[i] = 0.f;

    for (int i = 0; i < 16; i++) {
        int ntile = ns * 16 + i;
        s8v tAh[4], tAl[4];
#pragma unroll
        for (int kb = 0; kb < 4; kb++) {
            int off = ((kb * 256 + ntile) * 64 + lane) * 8;
            tAh[kb] = *reinterpret_cast<const s8v*>(thH + off);
            tAl[kb] = *reinterpret_cast<const s8v*>(thL + off);
        }
#pragma unroll
        for (int mt = 0; mt < 4; mt++) {
            f4v shh = (f4v){0.f, 0.f, 0.f, 0.f};
            f4v sx  = (f4v){0.f, 0.f, 0.f, 0.f};
#pragma unroll
            for (int kb = 0; kb < 4; kb++)
                shh = __builtin_amdgcn_mfma_f32_16x16x32_bf16(tAh[kb], pBh[mt][kb], shh, 0, 0, 0);
#pragma unroll
            for (int kb = 0; kb < 4; kb++) {
                sx = __builtin_amdgcn_mfma_f32_16x16x32_bf16(tAh[kb], pBl[mt][kb], sx, 0, 0, 0);
                sx = __builtin_amdgcn_mfma_f32_16x16x32_bf16(tAl[kb], pBh[mt][kb], sx, 0, 0, 0);
            }
            Lp[mt] += (__expf(shh[0] + sx[0]) + __expf(shh[1] + sx[1]))
                    + (__expf(shh[2] + sx[2]) + __expf(shh[3] + sx[3]));
        }
    }
#pragma unroll
    for (int mt = 0; mt < 4; mt++) {
        float v = Lp[mt];
        v += __shfl_xor(v, 16);
        v += __shfl_xor(v, 32);
        if (lane < 16) atomicAdd(&Lraw[b * NN + (mg * 4 + mt) * 16 + lane], v);
    }
}

// ---------- small path Phase 2b: G'[m,o] = G[m,o] / L[m] ------------------------
__global__ __launch_bounds__(256) void rescale_kernel(
    u16b* __restrict__ gB, const float* __restrict__ Lraw)
{
    int t = blockIdx.x * 256 + threadIdx.x;    // grid 1024
    int flat0 = t * 8;
    int b = flat0 >> 19;
    int rem = flat0 & ((NN * HIDD) - 1);
    int kb = rem >> 12;
    int lane = (rem >> 3) & 63;
    int qs = lane >> 4;
    int mbase = kb * 32 + qs * 4;
    const float* Lp = Lraw + b * NN + mbase;
    u16b* gp = gB + flat0;
    s8v g = *reinterpret_cast<const s8v*>(gp);
    s8v o;
#pragma unroll
    for (int j = 0; j < 8; j++) {
        float v = b2f((unsigned short)g[j]) / Lp[((j >> 2) << 4) + (j & 3)];
        o[j] = (short)f2b(v);
    }
    *reinterpret_cast<s8v*>(gp) = o;
}

// ---------- small path Phase 3: Out += softmax(S) @ G', fused S^T recompute -----
__global__ __launch_bounds__(256, 2) void attn_kernel(
    const u16b* __restrict__ thetaH, const u16b* __restrict__ thetaL,
    const u16b* __restrict__ phiH, const u16b* __restrict__ phiL,
    const u16b* __restrict__ gB, float* __restrict__ outAcc)
{
    int xcd = blockIdx.x & 7;                  // grid 1024
    int inner = blockIdx.x >> 3;               // 0..127
    int combo = xcd * 4 + (inner & 3);         // 0..31 = b*8+ms (XCD-pinned)
    int b = combo >> 3;
    int ms = combo & 7;                        // 8-way m-split
    int ng = inner >> 2;                       // 0..31
    int w = threadIdx.x >> 6;
    int lane = threadIdx.x & 63;
    int l15 = lane & 15, q = lane >> 4;
    int ntile0 = ng * 8 + w * 2;

    size_t boff = (size_t)b * (NN * HIDD);
    const u16b* thH = thetaH + boff; const u16b* thL = thetaL + boff;
    const u16b* phH = phiH + boff;   const u16b* phL = phiL + boff;
    const u16b* gp = gB + boff;

    s8v tBh[2][4], tBl[2][4];
#pragma unroll
    for (int nt = 0; nt < 2; nt++)
#pragma unroll
        for (int kb = 0; kb < 4; kb++) {
            int off = ((kb * 256 + ntile0 + nt) * 64 + lane) * 8;
            tBh[nt][kb] = *reinterpret_cast<const s8v*>(thH + off);
            tBl[nt][kb] = *reinterpret_cast<const s8v*>(thL + off);
        }

    f4v acc[2][8];
#pragma unroll
    for (int nt = 0; nt < 2; nt++)
#pragma unroll
        for (int i = 0; i < 8; i++) acc[nt][i] = (f4v){0.f, 0.f, 0.f, 0.f};

    for (int mt = 0; mt < 16; mt++) {
        int m0 = ms * 512 + mt * 32;
        s8v pf[2];
#pragma unroll
        for (int h = 0; h < 2; h++) {
            int mtile = (m0 >> 4) + h;
            s8v pAh[4], pAl[4];
#pragma unroll
            for (int kb = 0; kb < 4; kb++) {
                int off = ((kb * 256 + mtile) * 64 + lane) * 8;
                pAh[kb] = *reinterpret_cast<const s8v*>(phH + off);
                pAl[kb] = *reinterpret_cast<const s8v*>(phL + off);
            }
#pragma unroll
            for (int nt = 0; nt < 2; nt++) {
                f4v shh = (f4v){0.f, 0.f, 0.f, 0.f};
                f4v sx  = (f4v){0.f, 0.f, 0.f, 0.f};
#pragma unroll
                for (int kb = 0; kb < 4; kb++)
                    shh = __builtin_amdgcn_mfma_f32_16x16x32_bf16(pAh[kb], tBh[nt][kb], shh, 0, 0, 0);
#pragma unroll
                for (int kb = 0; kb < 4; kb++) {
                    sx = __builtin_amdgcn_mfma_f32_16x16x32_bf16(pAh[kb], tBl[nt][kb], sx, 0, 0, 0);
                    sx = __builtin_amdgcn_mfma_f32_16x16x32_bf16(pAl[kb], tBh[nt][kb], sx, 0, 0, 0);
                }
#pragma unroll
                for (int r = 0; r < 4; r++)
                    pf[nt][h * 4 + r] = (short)f2b(__expf(shh[r] + sx[r]));
            }
        }
        int kb2 = m0 >> 5;
#pragma unroll
        for (int ot = 0; ot < 8; ot++) {
            s8v gf = *reinterpret_cast<const s8v*>(gp + ((kb2 * 8 + ot) * 64 + lane) * 8);
#pragma unroll
            for (int nt = 0; nt < 2; nt++)
                acc[nt][ot] = __builtin_amdgcn_mfma_f32_16x16x32_bf16(pf[nt], gf, acc[nt][ot], 0, 0, 0);
        }
    }

    float* oa = outAcc + (size_t)b * (NN * HIDD);
#pragma unroll
    for (int nt = 0; nt < 2; nt++) {
        int n_base = (ntile0 + nt) * 16;
#pragma unroll
        for (int ot = 0; ot < 8; ot++) {
#pragma unroll
            for (int r = 0; r < 4; r++) {
                int n = n_base + q * 4 + r;
                int o = ot * 16 + l15;
                atomicAdd(&oa[swz(o, n, NN / 16)], acc[nt][ot][r]);
            }
        }
    }
}

// ---------- big path Phase 2: S-pass, pipelined, FULL 16B P stores --------------
// kb2-pair iterations (h=0,1 inner), phi prefetched one half-tile ahead.
// L via per-wave LDS rows -> private per-block Lpart slice (no atomics).
__global__ __launch_bounds__(256, 2) void spass_kernel(
    const u16b* __restrict__ thetaH, const u16b* __restrict__ thetaL,
    const u16b* __restrict__ phiH, const u16b* __restrict__ phiL,
    u16b* __restrict__ P, float* __restrict__ Lpart)
{
    int xcd = blockIdx.x & 7;                  // grid 2048
    int inner = blockIdx.x >> 3;               // 0..255
    int combo = xcd * 8 + (inner & 7);         // 0..63 = b*16+ms
    int b = combo >> 4;
    int ms = combo & 15;                       // 16-way m-split
    int ng = inner >> 3;                       // 0..31
    int w = threadIdx.x >> 6;
    int lane = threadIdx.x & 63;
    int l15 = lane & 15, q = lane >> 4;
    int ntile0 = ng * 8 + w * 2;

    size_t boff = (size_t)b * (NN * HIDD);
    const u16b* thH = thetaH + boff; const u16b* thL = thetaL + boff;
    const u16b* phH = phiH + boff;   const u16b* phL = phiL + boff;
    u16b* Pb = P + (size_t)b * NN * NN;

    __shared__ float Lacc[4][256];             // [wave][m_local], each written once

    s8v tBh[2][4], tBl[2][4];
#pragma unroll
    for (int nt = 0; nt < 2; nt++)
#pragma unroll
        for (int kb = 0; kb < 4; kb++) {
            int off = ((kb * 256 + ntile0 + nt) * 64 + lane) * 8;
            tBh[nt][kb] = *reinterpret_cast<const s8v*>(thH + off);
            tBl[nt][kb] = *reinterpret_cast<const s8v*>(thL + off);
        }

    int ph = ng & 7;                           // stagger phase (kb2 granularity)
    s8v pAh[4], pAl[4];
    {
        int mtile = ms * 16 + ph * 2;          // i2=0, h=0
#pragma unroll
        for (int kb = 0; kb < 4; kb++) {
            int off = ((kb * 256 + mtile) * 64 + lane) * 8;
            pAh[kb] = *reinterpret_cast<const s8v*>(phH + off);
            pAl[kb] = *reinterpret_cast<const s8v*>(phL + off);
        }
    }

    for (int i2 = 0; i2 < 8; i2++) {
        int mtr = (i2 + ph) & 7;
        s8v pf[2];
#pragma unroll
        for (int h = 0; h < 2; h++) {
            // prefetch next half-tile's phi (wraps harmlessly on last iter)
            int nmtile = (h == 0) ? (ms * 16 + mtr * 2 + 1)
                                  : (ms * 16 + (((i2 + 1 + ph) & 7)) * 2);
            s8v pAhN[4], pAlN[4];
#pragma unroll
            for (int kb = 0; kb < 4; kb++) {
                int off = ((kb * 256 + nmtile) * 64 + lane) * 8;
                pAhN[kb] = *reinterpret_cast<const s8v*>(phH + off);
                pAlN[kb] = *reinterpret_cast<const s8v*>(phL + off);
            }
            // S^T tile for both ntiles (split-bf16, interleaved)
            f4v s0h = (f4v){0.f, 0.f, 0.f, 0.f};
            f4v s1h = (f4v){0.f, 0.f, 0.f, 0.f};
            f4v s0x = (f4v){0.f, 0.f, 0.f, 0.f};
            f4v s1x = (f4v){0.f, 0.f, 0.f, 0.f};
#pragma unroll
            for (int kb = 0; kb < 4; kb++) {
                s0h = __builtin_amdgcn_mfma_f32_16x16x32_bf16(pAh[kb], tBh[0][kb], s0h, 0, 0, 0);
                s1h = __builtin_amdgcn_mfma_f32_16x16x32_bf16(pAh[kb], tBh[1][kb], s1h, 0, 0, 0);
            }
#pragma unroll
            for (int kb = 0; kb < 4; kb++) {
                s0x = __builtin_amdgcn_mfma_f32_16x16x32_bf16(pAh[kb], tBl[0][kb], s0x, 0, 0, 0);
                s1x = __builtin_amdgcn_mfma_f32_16x16x32_bf16(pAh[kb], tBl[1][kb], s1x, 0, 0, 0);
                s0x = __builtin_amdgcn_mfma_f32_16x16x32_bf16(pAl[kb], tBh[0][kb], s0x, 0, 0, 0);
                s1x = __builtin_amdgcn_mfma_f32_16x16x32_bf16(pAl[kb], tBh[1][kb], s1x, 0, 0, 0);
            }
            float ev0[4], ev1[4];
#pragma unroll
            for (int r = 0; r < 4; r++) {
                ev0[r] = __expf(s0h[r] + s0x[r]);
                ev1[r] = __expf(s1h[r] + s1x[r]);
            }
#pragma unroll
            for (int r = 0; r < 4; r++) {
                pf[0][h * 4 + r] = (short)f2b(ev0[r]);
                pf[1][h * 4 + r] = (short)f2b(ev1[r]);
            }
            // column-sum over this wave's 32 n (2 nt x 16 l15-lanes)
            float cs[4];
#pragma unroll
            for (int r = 0; r < 4; r++) {
                cs[r] = ev0[r] + ev1[r];
                cs[r] += __shfl_xor(cs[r], 1);
                cs[r] += __shfl_xor(cs[r], 2);
                cs[r] += __shfl_xor(cs[r], 4);
                cs[r] += __shfl_xor(cs[r], 8);
            }
            if (l15 == 0) {
#pragma unroll
                for (int r = 0; r < 4; r++)
                    Lacc[w][mtr * 32 + h * 16 + q * 4 + r] = cs[r];
            }
            // rotate prefetch registers
#pragma unroll
            for (int kb = 0; kb < 4; kb++) { pAh[kb] = pAhN[kb]; pAl[kb] = pAlN[kb]; }
        }
        // full 16B store per kb2 (both halves assembled)
        int kb2 = ms * 8 + mtr;
#pragma unroll
        for (int nt = 0; nt < 2; nt++)
            *reinterpret_cast<s8v*>(
                Pb + ((size_t)(kb2 * 256 + ntile0 + nt) * 64 + lane) * 8) = pf[nt];
    }
    __syncthreads();
    {
        int t = threadIdx.x;                   // 0..255 == m_local
        float s = (Lacc[0][t] + Lacc[1][t]) + (Lacc[2][t] + Lacc[3][t]);
        Lpart[((size_t)(combo * 32 + ng)) * 256 + t] = s;
    }
}

// ---------- big path Phase 2b: fused L-sum + G rescale --------------------------
__global__ __launch_bounds__(256) void lrescale_kernel(
    u16b* __restrict__ gB, const float* __restrict__ Lpart)
{
    int t = blockIdx.x;                        // grid 1024
    int b = t >> 8;
    int kb = (t & 255) >> 1;                   // m>>5, 0..127
    int combo = b * 16 + (kb >> 3);
    int mlbase = (kb & 7) * 32;
    __shared__ float sLp[32][9];
    __shared__ float sL[32];
    int ti = threadIdx.x;
    {
        int mi = ti & 31;                      // = qs*8 + h*4 + r
        int ngp = ti >> 5;                     // 0..7
        int qs = mi >> 3, h = (mi >> 2) & 1, r = mi & 3;
        int ml = mlbase + qs * 4 + h * 16 + r;
        const float* base = Lpart + ((size_t)(combo * 32 + ngp * 4)) * 256 + ml;
        sLp[mi][ngp] = (base[0] + base[256]) + (base[512] + base[768]);
    }
    __syncthreads();
    if (ti < 32) {
        float s = 0.f;
#pragma unroll
        for (int k = 0; k < 8; k++) s += sLp[ti][k];
        sL[ti] = s;
    }
    __syncthreads();
    size_t flat0 = (size_t)b * (NN * HIDD) + (size_t)(t & 255) * 2048 + (size_t)ti * 8;
    int lane = ti & 63;
    int qs = lane >> 4;
    u16b* gp = gB + flat0;
    s8v g = *reinterpret_cast<const s8v*>(gp);
    s8v o;
#pragma unroll
    for (int j = 0; j < 8; j++) {
        int mi = qs * 8 + ((j >> 2) << 2) + (j & 3);
        float v = b2f((unsigned short)g[j]) / sL[mi];
        o[j] = (short)f2b(v);
    }
    *reinterpret_cast<s8v*>(gp) = o;
}

// ---------- big path Phase 3: partial[ms] = P-slice @ G' (NO atomics) -----------
__global__ __launch_bounds__(256, 4) void pv_kernel(
    const u16b* __restrict__ P, const u16b* __restrict__ gB, u16b* __restrict__ pvPart)
{
    int xcd = blockIdx.x & 7;                  // grid 1024
    int inner = blockIdx.x >> 3;               // 0..127
    int combo = xcd * 2 + (inner & 1);         // 0..15 = b*4+ms (XCD-pinned)
    int b = combo >> 2;
    int ms = combo & 3;                        // 4-way m-split
    int ng = inner >> 1;                       // 0..63
    int w = threadIdx.x >> 6;
    int lane = threadIdx.x & 63;
    int l15 = lane & 15, q = lane >> 4;
    int ntile = ng * 4 + w;                    // 0..255, one ntile per wave

    const u16b* Pb = P + (size_t)b * NN * NN;
    const u16b* gp = gB + (size_t)b * (NN * HIDD);

    f4v acc[8];
#pragma unroll
    for (int i = 0; i < 8; i++) acc[i] = (f4v){0.f, 0.f, 0.f, 0.f};

    int ph = ng & 31;                          // stagger phase
    int k0 = ms * 32 + ph;
    int k1 = ms * 32 + ((ph + 1) & 31);
    s8v pcur = *reinterpret_cast<const s8v*>(Pb + ((size_t)(k0 * 256 + ntile) * 64 + lane) * 8);
    s8v pnx1 = *reinterpret_cast<const s8v*>(Pb + ((size_t)(k1 * 256 + ntile) * 64 + lane) * 8);

    for (int it = 0; it < 32; it++) {
        int kb2  = ms * 32 + ((it + ph) & 31);
        int kb2n = ms * 32 + ((it + 2 + ph) & 31);
        s8v pnx2 = *reinterpret_cast<const s8v*>(Pb + ((size_t)(kb2n * 256 + ntile) * 64 + lane) * 8);
#pragma unroll
        for (int ot = 0; ot < 8; ot++) {
            s8v gf = *reinterpret_cast<const s8v*>(gp + ((kb2 * 8 + ot) * 64 + lane) * 8);
            acc[ot] = __builtin_amdgcn_mfma_f32_16x16x32_bf16(pcur, gf, acc[ot], 0, 0, 0);
        }
        pcur = pnx1;
        pnx1 = pnx2;
    }

    u16b* pp = pvPart + (size_t)ms * ((size_t)BB * NN * HIDD) + (size_t)b * (NN * HIDD);
    int n_base = ntile * 16;
#pragma unroll
    for (int ot = 0; ot < 8; ot++) {
#pragma unroll
        for (int r = 0; r < 4; r++) {
            int n = n_base + q * 4 + r;
            int o = ot * 16 + l15;
            pp[swz(o, n, NN / 16)] = f2b(acc[ot][r]);
        }
    }
}

// ---------- big path Phase 4: y = x + w_mask @ (sum of partials)^T --------------
// Plain bf16 (no splits): added error ~1e-3 << threshold; max|y| ~ 3.6.
__global__ __launch_bounds__(256) void final_big_kernel(
    const float* __restrict__ x, const u16b* __restrict__ wmB,
    const u16b* __restrict__ pvPart, float* __restrict__ y)
{
    int wave = blockIdx.x * 4 + (threadIdx.x >> 6);   // 4096 waves
    int lane = threadIdx.x & 63;
    int l15 = lane & 15, q = lane >> 4;
    int b = wave >> 10;
    int rem = wave & 1023;
    int ctile = rem >> 6;
    int n64 = rem & 63;
    const size_t pstride = (size_t)BB * NN * HIDD;
    const u16b* pb = pvPart + (size_t)b * (NN * HIDD);
    const float* xb = x + (size_t)b * CC * NN;
    float* yb = y + (size_t)b * CC * NN;
    int c0 = ctile * 16;

    s8v aB[4];
#pragma unroll
    for (int kb = 0; kb < 4; kb++)
        aB[kb] = *reinterpret_cast<const s8v*>(wmB + (c0 + l15) * HIDD + kb * 32 + q * 8);

#pragma unroll
    for (int nt = 0; nt < 4; nt++) {
        int ntile = n64 * 4 + nt;
        f4v acc = (f4v){0.f, 0.f, 0.f, 0.f};
#pragma unroll
        for (int kb = 0; kb < 4; kb++) {
            size_t fo = ((size_t)(kb * 256 + ntile) * 64 + lane) * 8;
            float s[8];
#pragma unroll
            for (int j = 0; j < 8; j++) s[j] = 0.f;
#pragma unroll
            for (int p = 0; p < 4; p++) {
                s8v v = *reinterpret_cast<const s8v*>(pb + p * pstride + fo);
#pragma unroll
                for (int j = 0; j < 8; j++) s[j] += b2f((unsigned short)v[j]);
            }
            s8v bv;
#pragma unroll
            for (int j = 0; j < 8; j++) bv[j] = (short)f2b(s[j]);
            acc = __builtin_amdgcn_mfma_f32_16x16x32_bf16(aB[kb], bv, acc, 0, 0, 0);
        }
#pragma unroll
        for (int r = 0; r < 4; r++) {
            int c = c0 + q * 4 + r;
            int n = ntile * 16 + l15;
            size_t idx = (size_t)c * NN + n;
            yb[idx] = xb[idx] + acc[r];
        }
    }
}

// ---------- small path Phase 4: y = x + w_mask @ Out^T --------------------------
__global__ __launch_bounds__(256) void final_kernel(
    const float* __restrict__ x, const u16b* __restrict__ wmB,
    const float* __restrict__ outAcc, float* __restrict__ y)
{
    int wave = blockIdx.x * 4 + (threadIdx.x >> 6);   // 4096 waves
    int lane = threadIdx.x & 63;
    int l15 = lane & 15, q = lane >> 4;
    int b = wave >> 10;
    int rem = wave & 1023;
    int ctile = rem >> 6;
    int n64 = rem & 63;
    const float* oa = outAcc + (size_t)b * (NN * HIDD);
    const float* xb = x + (size_t)b * CC * NN;
    float* yb = y + (size_t)b * CC * NN;
    int c0 = ctile * 16;

    s8v aB[4];
#pragma unroll
    for (int kb = 0; kb < 4; kb++)
        aB[kb] = *reinterpret_cast<const s8v*>(wmB + (c0 + l15) * HIDD + kb * 32 + q * 8);

#pragma unroll
    for (int nt = 0; nt < 4; nt++) {
        int ntile = n64 * 4 + nt;
        f4v acc = (f4v){0.f, 0.f, 0.f, 0.f};
#pragma unroll
        for (int kb = 0; kb < 4; kb++) {
            const float* bp = oa + ((size_t)(kb * 256 + ntile) * 64 + lane) * 8;
            f4v b0 = *reinterpret_cast<const f4v*>(bp);
            f4v b1 = *reinterpret_cast<const f4v*>(bp + 4);
            s8v bv;
#pragma unroll
            for (int j = 0; j < 4; j++) {
                bv[j]     = (short)f2b(b0[j]);
                bv[j + 4] = (short)f2b(b1[j]);
            }
            acc = __builtin_amdgcn_mfma_f32_16x16x32_bf16(aB[kb], bv, acc, 0, 0, 0);
        }
#pragma unroll
        for (int r = 0; r < 4; r++) {
            int c = c0 + q * 4 + r;
            int n = ntile * 16 + l15;
            size_t idx = (size_t)c * NN + n;
            yb[idx] = xb[idx] + acc[r];
        }
    }
}

extern "C" void kernel_launch(void* const* d_in, const int* in_sizes, int n_in,
                              void* d_out, int out_size, void* d_ws, size_t ws_size,
                              hipStream_t stream)
{
    (void)in_sizes; (void)n_in; (void)out_size;
    const float* x  = (const float*)d_in[0];
    const float* wt = (const float*)d_in[1];
    const float* wp = (const float*)d_in[2];
    const float* wg = (const float*)d_in[3];
    const float* wm = (const float*)d_in[4];
    float* y = (float*)d_out;

    char* ws = (char*)d_ws;
    const size_t MB = 1 << 20;
    u16b* thetaH = (u16b*)(ws + 0 * MB);
    u16b* thetaL = (u16b*)(ws + 4 * MB);
    u16b* phiH   = (u16b*)(ws + 8 * MB);
    u16b* phiL   = (u16b*)(ws + 12 * MB);
    u16b* pvPart = (u16b*)(ws + 0 * MB);                   // 16 MB, overlays theta/phi
    u16b* gB     = (u16b*)(ws + 16 * MB);
    float* outAcc = (float*)(ws + 20 * MB);                // 8 MB fp32 (small path)
    float* Lraw   = (float*)(ws + 28 * MB);                // 64 KB (small path)
    char* wbase = ws + 28 * MB + (64 << 10);
    u16b* wHb = (u16b*)(wbase);                            // 128 KB
    u16b* wLb = (u16b*)(wbase + (128 << 10));              // 128 KB
    u16b* wgB = (u16b*)(wbase + (256 << 10));              // 64 KB
    u16b* wmH = (u16b*)(wbase + (320 << 10));              // 64 KB
    u16b* wmL = (u16b*)(wbase + (384 << 10));              // 64 KB
    float* Lpart = (float*)(ws + 30 * MB);                 // 2 MB (big path)
    u16b* P   = (u16b*)(ws + 32 * MB);                     // 134.2 MB (big path)

    const size_t need_big = 32 * MB + (size_t)BB * NN * NN * sizeof(u16b);
    const bool big = ws_size >= need_big;

    hipLaunchKernelGGL(prep_kernel, dim3(128), dim3(256), 0, stream,
                       wt, wp, wg, wm, wHb, wLb, wgB, wmH, wmL);
    hipLaunchKernelGGL(proj_kernel, dim3(512), dim3(256), 0, stream,
                       x, wHb, wLb, wgB, thetaH, thetaL, phiH, phiL, gB);

    if (big) {
        hipLaunchKernelGGL(spass_kernel,    dim3(2048), dim3(256), 0, stream,
                           thetaH, thetaL, phiH, phiL, P, Lpart);
        hipLaunchKernelGGL(lrescale_kernel, dim3(1024), dim3(256), 0, stream, gB, Lpart);
        // pv overwrites the theta/phi region (dead after spass) with bf16 partials
        hipLaunchKernelGGL(pv_kernel,       dim3(1024), dim3(256), 0, stream, P, gB, pvPart);
        hipLaunchKernelGGL(final_big_kernel, dim3(1024), dim3(256), 0, stream,
                           x, wmH, pvPart, y);
    } else {
        hipMemsetAsync(Lraw, 0, (size_t)BB * NN * sizeof(float), stream);
        hipMemsetAsync(outAcc, 0, (size_t)BB * NN * HIDD * sizeof(float), stream);
        hipLaunchKernelGGL(stats_kernel,   dim3(1024), dim3(256), 0, stream,
                           thetaH, thetaL, phiH, phiL, Lraw);
        hipLaunchKernelGGL(rescale_kernel, dim3(1024), dim3(256), 0, stream, gB, Lraw);
        hipLaunchKernelGGL(attn_kernel,    dim3(1024), dim3(256), 0, stream,
                           thetaH, thetaL, phiH, phiL, gB, outAcc);
        hipLaunchKernelGGL(final_kernel,   dim3(1024), dim3(256), 0, stream,
                           x, wmH, outAcc, y);
    }
}

// Round 11
// 200.256 us; speedup vs baseline: 1.2390x; 1.2164x over previous
//
#include <hip/hip_runtime.h>

#define BB 4
#define CC 256
#define HIDD 128
#define NN 4096

typedef short s8v __attribute__((ext_vector_type(8)));
typedef _Float16 h8v __attribute__((ext_vector_type(8)));
typedef float f4v __attribute__((ext_vector_type(4)));
typedef unsigned short u16b;

static __device__ __forceinline__ float b2f(unsigned short u) {
    union { unsigned int i; float f; } v; v.i = ((unsigned int)u) << 16; return v.f;
}
static __device__ __forceinline__ unsigned short f2b(float f) {
    union { float f; unsigned int i; } v; v.f = f;
    unsigned int i = v.i;
    return (unsigned short)((i + 0x7fffu + ((i >> 16) & 1u)) >> 16);
}
static __device__ __forceinline__ u16b f2h_bits(float f) {
    union { _Float16 h; u16b u; } v; v.h = (_Float16)f; return v.u;
}

// Standard swizzled fragment layout for 16x16x32 MFMA operands (16-bit dtypes).
__device__ __forceinline__ int swz(int k, int rc, int CB) {
    return (((k >> 5) * CB + (rc >> 4)) * 64 + ((k >> 3) & 3) * 16 + (rc & 15)) * 8 + (k & 7);
}
// Permuted swizzle for G': k-slot (q,j) <-> m_local = (j>>2)*16 + q*4 + (j&3).
__device__ __forceinline__ int gswz(int m, int o) {
    int kb = m >> 5, mm = m & 31;
    int qs = (mm >> 2) & 3;
    int js = ((mm >> 4) & 1) * 4 + (mm & 3);
    return ((kb * 8 + (o >> 4)) * 64 + qs * 16 + (o & 15)) * 8 + js;
}

// ---------- Phase 0: weights -> fp16 (theta/phi/g) and bf16 (mask) --------------
__global__ __launch_bounds__(256) void prep_kernel(
    const float* __restrict__ wt, const float* __restrict__ wp,
    const float* __restrict__ wg, const float* __restrict__ wm,
    u16b* __restrict__ wF, u16b* __restrict__ wmB)
{
    int t = blockIdx.x * 256 + threadIdx.x;   // grid 128 -> 32768 = HID*CC
    wF[t]         = f2h_bits(wt[t]);
    wF[32768 + t] = f2h_bits(wp[t]);
    wF[65536 + t] = f2h_bits(wg[t]);
    wmB[t]        = f2b(wm[t]);
}

// ---------- Phase 1: Theta/Phi (fp16, swizzled) and G (bf16, perm-swizzled) -----
// All MFMAs fp16 single-pass (2^-11 operand precision).
__global__ __launch_bounds__(256) void proj_kernel(
    const float* __restrict__ x, const u16b* __restrict__ wF,
    u16b* __restrict__ thetaF, u16b* __restrict__ phiF, u16b* __restrict__ gB)
{
    int wave = blockIdx.x * 4 + (threadIdx.x >> 6);   // 2048 waves
    int lane = threadIdx.x & 63;
    int l15 = lane & 15, q = lane >> 4;
    int b = wave >> 9;
    int rem = wave & 511;
    int ntile = rem >> 1;
    int half = rem & 1;                                // ot range half*4..half*4+3
    int n0 = ntile << 4;
    const float* xb = x + (size_t)b * CC * NN;

    f4v acc[3][4];
#pragma unroll
    for (int m = 0; m < 3; m++)
#pragma unroll
        for (int i = 0; i < 4; i++) acc[m][i] = (f4v){0.f, 0.f, 0.f, 0.f};

    float xv[8];
    {
        const float* xp = xb + (size_t)(q * 8) * NN + n0 + l15;
#pragma unroll
        for (int j = 0; j < 8; j++) xv[j] = xp[(size_t)j * NN];
    }

    for (int kc = 0; kc < 8; kc++) {
        int c0 = kc * 32;
        float xn[8];
        if (kc < 7) {
            const float* xp = xb + (size_t)(c0 + 32 + q * 8) * NN + n0 + l15;
#pragma unroll
            for (int j = 0; j < 8; j++) xn[j] = xp[(size_t)j * NN];
        }
        h8v bx;
#pragma unroll
        for (int j = 0; j < 8; j++) bx[j] = (_Float16)xv[j];
#pragma unroll
        for (int mat = 0; mat < 3; mat++) {
#pragma unroll
            for (int otl = 0; otl < 4; otl++) {
                int ot = half * 4 + otl;
                const h8v* ap = reinterpret_cast<const h8v*>(
                    wF + mat * 32768 + (ot * 16 + l15) * CC + c0 + q * 8);
                acc[mat][otl] = __builtin_amdgcn_mfma_f32_16x16x32_f16(*ap, bx, acc[mat][otl], 0, 0, 0);
            }
        }
        if (kc < 7) {
#pragma unroll
            for (int j = 0; j < 8; j++) xv[j] = xn[j];
        }
    }

    size_t boff = (size_t)b * (NN * HIDD);
#pragma unroll
    for (int otl = 0; otl < 4; otl++) {
#pragma unroll
        for (int r = 0; r < 4; r++) {
            int o = (half * 4 + otl) * 16 + q * 4 + r;   // C/D row (hid)
            int n = n0 + l15;                             // C/D col (spatial)
            int offTP = swz(o, n, NN / 16);
            thetaF[boff + offTP] = f2h_bits(acc[0][otl][r]);
            phiF[boff + offTP]   = f2h_bits(acc[1][otl][r]);
            gB[boff + gswz(n, o)] = f2b(acc[2][otl][r]);  // bf16: G' needs range
        }
    }
}

// ---------- small path Phase 2: Lraw[m] = sum_n e^{s[n][m]} (fp16 S) ------------
__global__ __launch_bounds__(256, 2) void stats_kernel(
    const u16b* __restrict__ thetaF, const u16b* __restrict__ phiF,
    float* __restrict__ Lraw)
{
    int xcd = blockIdx.x & 7;                  // grid 1024
    int inner = blockIdx.x >> 3;               // 0..127
    int b = xcd >> 1;
    int su = (xcd & 1) * 128 + inner;          // 0..255 within batch
    int w = threadIdx.x >> 6;
    int wu = su * 4 + w;                       // 0..1023
    int mg = wu >> 4;                          // 64 groups of 4 mtiles
    int ns = wu & 15;                          // 16-way n-split
    int lane = threadIdx.x & 63;

    size_t boff = (size_t)b * (NN * HIDD);
    const u16b* thF = thetaF + boff;
    const u16b* phF = phiF + boff;

    h8v pB[4][4];
#pragma unroll
    for (int mt = 0; mt < 4; mt++)
#pragma unroll
        for (int kb = 0; kb < 4; kb++)
            pB[mt][kb] = *reinterpret_cast<const h8v*>(phF + ((kb * 256 + (mg * 4 + mt)) * 64 + lane) * 8);

    float Lp[4];
#pragma unroll
    for (int i = 0; i < 4; i++) Lp[i] = 0.f;

    for (int i = 0; i < 16; i++) {
        int ntile = ns * 16 + i;
        h8v tA[4];
#pragma unroll
        for (int kb = 0; kb < 4; kb++)
            tA[kb] = *reinterpret_cast<const h8v*>(thF + ((kb * 256 + ntile) * 64 + lane) * 8);
#pragma unroll
        for (int mt = 0; mt < 4; mt++) {
            f4v s = (f4v){0.f, 0.f, 0.f, 0.f};
#pragma unroll
            for (int kb = 0; kb < 4; kb++)
                s = __builtin_amdgcn_mfma_f32_16x16x32_f16(tA[kb], pB[mt][kb], s, 0, 0, 0);
            Lp[mt] += (__expf(s[0]) + __expf(s[1])) + (__expf(s[2]) + __expf(s[3]));
        }
    }
#pragma unroll
    for (int mt = 0; mt < 4; mt++) {
        float v = Lp[mt];
        v += __shfl_xor(v, 16);
        v += __shfl_xor(v, 32);
        if (lane < 16) atomicAdd(&Lraw[b * NN + (mg * 4 + mt) * 16 + lane], v);
    }
}

// ---------- small path Phase 2b: G'[m,o] = G[m,o] / L[m] ------------------------
__global__ __launch_bounds__(256) void rescale_kernel(
    u16b* __restrict__ gB, const float* __restrict__ Lraw)
{
    int t = blockIdx.x * 256 + threadIdx.x;    // grid 1024
    int flat0 = t * 8;
    int b = flat0 >> 19;
    int rem = flat0 & ((NN * HIDD) - 1);
    int kb = rem >> 12;
    int lane = (rem >> 3) & 63;
    int qs = lane >> 4;
    int mbase = kb * 32 + qs * 4;
    const float* Lp = Lraw + b * NN + mbase;
    u16b* gp = gB + flat0;
    s8v g = *reinterpret_cast<const s8v*>(gp);
    s8v o;
#pragma unroll
    for (int j = 0; j < 8; j++) {
        float v = b2f((unsigned short)g[j]) / Lp[((j >> 2) << 4) + (j & 3)];
        o[j] = (short)f2b(v);
    }
    *reinterpret_cast<s8v*>(gp) = o;
}

// ---------- small path Phase 3: Out += softmax(S) @ G' (fp16 S, bf16 PV) --------
__global__ __launch_bounds__(256, 2) void attn_kernel(
    const u16b* __restrict__ thetaF, const u16b* __restrict__ phiF,
    const u16b* __restrict__ gB, float* __restrict__ outAcc)
{
    int xcd = blockIdx.x & 7;                  // grid 1024
    int inner = blockIdx.x >> 3;               // 0..127
    int combo = xcd * 4 + (inner & 3);         // 0..31 = b*8+ms (XCD-pinned)
    int b = combo >> 3;
    int ms = combo & 7;                        // 8-way m-split
    int ng = inner >> 2;                       // 0..31
    int w = threadIdx.x >> 6;
    int lane = threadIdx.x & 63;
    int l15 = lane & 15, q = lane >> 4;
    int ntile0 = ng * 8 + w * 2;

    size_t boff = (size_t)b * (NN * HIDD);
    const u16b* thF = thetaF + boff;
    const u16b* phF = phiF + boff;
    const u16b* gp = gB + boff;

    h8v tB[2][4];
#pragma unroll
    for (int nt = 0; nt < 2; nt++)
#pragma unroll
        for (int kb = 0; kb < 4; kb++)
            tB[nt][kb] = *reinterpret_cast<const h8v*>(thF + ((kb * 256 + ntile0 + nt) * 64 + lane) * 8);

    f4v acc[2][8];
#pragma unroll
    for (int nt = 0; nt < 2; nt++)
#pragma unroll
        for (int i = 0; i < 8; i++) acc[nt][i] = (f4v){0.f, 0.f, 0.f, 0.f};

    for (int mt = 0; mt < 16; mt++) {
        int m0 = ms * 512 + mt * 32;
        s8v pf[2];
#pragma unroll
        for (int h = 0; h < 2; h++) {
            int mtile = (m0 >> 4) + h;
            h8v pA[4];
#pragma unroll
            for (int kb = 0; kb < 4; kb++)
                pA[kb] = *reinterpret_cast<const h8v*>(phF + ((kb * 256 + mtile) * 64 + lane) * 8);
#pragma unroll
            for (int nt = 0; nt < 2; nt++) {
                f4v s = (f4v){0.f, 0.f, 0.f, 0.f};
#pragma unroll
                for (int kb = 0; kb < 4; kb++)
                    s = __builtin_amdgcn_mfma_f32_16x16x32_f16(pA[kb], tB[nt][kb], s, 0, 0, 0);
#pragma unroll
                for (int r = 0; r < 4; r++)
                    pf[nt][h * 4 + r] = (short)f2b(__expf(s[r]));
            }
        }
        int kb2 = m0 >> 5;
#pragma unroll
        for (int ot = 0; ot < 8; ot++) {
            s8v gf = *reinterpret_cast<const s8v*>(gp + ((kb2 * 8 + ot) * 64 + lane) * 8);
#pragma unroll
            for (int nt = 0; nt < 2; nt++)
                acc[nt][ot] = __builtin_amdgcn_mfma_f32_16x16x32_bf16(pf[nt], gf, acc[nt][ot], 0, 0, 0);
        }
    }

    float* oa = outAcc + (size_t)b * (NN * HIDD);
#pragma unroll
    for (int nt = 0; nt < 2; nt++) {
        int n_base = (ntile0 + nt) * 16;
#pragma unroll
        for (int ot = 0; ot < 8; ot++) {
#pragma unroll
            for (int r = 0; r < 4; r++) {
                int n = n_base + q * 4 + r;
                int o = ot * 16 + l15;
                atomicAdd(&oa[swz(o, n, NN / 16)], acc[nt][ot][r]);
            }
        }
    }
}

// ---------- big path Phase 2: S-pass fp16, pipelined, full 16B P stores ---------
// kb2-pair iterations (h=0,1 inner), phi prefetched one half-tile ahead.
// L via per-wave LDS rows -> private per-block Lpart slice (no atomics).
__global__ __launch_bounds__(256, 2) void spass_kernel(
    const u16b* __restrict__ thetaF, const u16b* __restrict__ phiF,
    u16b* __restrict__ P, float* __restrict__ Lpart)
{
    int xcd = blockIdx.x & 7;                  // grid 2048
    int inner = blockIdx.x >> 3;               // 0..255
    int combo = xcd * 8 + (inner & 7);         // 0..63 = b*16+ms
    int b = combo >> 4;
    int ms = combo & 15;                       // 16-way m-split
    int ng = inner >> 3;                       // 0..31
    int w = threadIdx.x >> 6;
    int lane = threadIdx.x & 63;
    int l15 = lane & 15, q = lane >> 4;
    int ntile0 = ng * 8 + w * 2;

    size_t boff = (size_t)b * (NN * HIDD);
    const u16b* thF = thetaF + boff;
    const u16b* phF = phiF + boff;
    u16b* Pb = P + (size_t)b * NN * NN;

    __shared__ float Lacc[4][256];             // [wave][m_local], each written once

    h8v tB[2][4];
#pragma unroll
    for (int nt = 0; nt < 2; nt++)
#pragma unroll
        for (int kb = 0; kb < 4; kb++)
            tB[nt][kb] = *reinterpret_cast<const h8v*>(thF + ((kb * 256 + ntile0 + nt) * 64 + lane) * 8);

    int ph = ng & 7;                           // stagger phase (kb2 granularity)
    h8v pA[4];
    {
        int mtile = ms * 16 + ph * 2;          // i2=0, h=0
#pragma unroll
        for (int kb = 0; kb < 4; kb++)
            pA[kb] = *reinterpret_cast<const h8v*>(phF + ((kb * 256 + mtile) * 64 + lane) * 8);
    }

    for (int i2 = 0; i2 < 8; i2++) {
        int mtr = (i2 + ph) & 7;
        s8v pf[2];
#pragma unroll
        for (int h = 0; h < 2; h++) {
            // prefetch next half-tile's phi (wraps harmlessly on last iter)
            int nmtile = (h == 0) ? (ms * 16 + mtr * 2 + 1)
                                  : (ms * 16 + (((i2 + 1 + ph) & 7)) * 2);
            h8v pAN[4];
#pragma unroll
            for (int kb = 0; kb < 4; kb++)
                pAN[kb] = *reinterpret_cast<const h8v*>(phF + ((kb * 256 + nmtile) * 64 + lane) * 8);
            // S^T tile for both ntiles (fp16, interleaved)
            f4v s0 = (f4v){0.f, 0.f, 0.f, 0.f};
            f4v s1 = (f4v){0.f, 0.f, 0.f, 0.f};
#pragma unroll
            for (int kb = 0; kb < 4; kb++) {
                s0 = __builtin_amdgcn_mfma_f32_16x16x32_f16(pA[kb], tB[0][kb], s0, 0, 0, 0);
                s1 = __builtin_amdgcn_mfma_f32_16x16x32_f16(pA[kb], tB[1][kb], s1, 0, 0, 0);
            }
            float ev0[4], ev1[4];
#pragma unroll
            for (int r = 0; r < 4; r++) {
                ev0[r] = __expf(s0[r]);
                ev1[r] = __expf(s1[r]);
            }
#pragma unroll
            for (int r = 0; r < 4; r++) {
                pf[0][h * 4 + r] = (short)f2b(ev0[r]);
                pf[1][h * 4 + r] = (short)f2b(ev1[r]);
            }
            // column-sum over this wave's 32 n (2 nt x 16 l15-lanes)
            float cs[4];
#pragma unroll
            for (int r = 0; r < 4; r++) {
                cs[r] = ev0[r] + ev1[r];
                cs[r] += __shfl_xor(cs[r], 1);
                cs[r] += __shfl_xor(cs[r], 2);
                cs[r] += __shfl_xor(cs[r], 4);
                cs[r] += __shfl_xor(cs[r], 8);
            }
            if (l15 == 0) {
#pragma unroll
                for (int r = 0; r < 4; r++)
                    Lacc[w][mtr * 32 + h * 16 + q * 4 + r] = cs[r];
            }
            // rotate prefetch registers
#pragma unroll
            for (int kb = 0; kb < 4; kb++) pA[kb] = pAN[kb];
        }
        // full 16B store per kb2 (both halves assembled)
        int kb2 = ms * 8 + mtr;
#pragma unroll
        for (int nt = 0; nt < 2; nt++)
            *reinterpret_cast<s8v*>(
                Pb + ((size_t)(kb2 * 256 + ntile0 + nt) * 64 + lane) * 8) = pf[nt];
    }
    __syncthreads();
    {
        int t = threadIdx.x;                   // 0..255 == m_local
        float s = (Lacc[0][t] + Lacc[1][t]) + (Lacc[2][t] + Lacc[3][t]);
        Lpart[((size_t)(combo * 32 + ng)) * 256 + t] = s;
    }
}

// ---------- big path Phase 2b: fused L-sum + G rescale --------------------------
__global__ __launch_bounds__(256) void lrescale_kernel(
    u16b* __restrict__ gB, const float* __restrict__ Lpart)
{
    int t = blockIdx.x;                        // grid 1024
    int b = t >> 8;
    int kb = (t & 255) >> 1;                   // m>>5, 0..127
    int combo = b * 16 + (kb >> 3);
    int mlbase = (kb & 7) * 32;
    __shared__ float sLp[32][9];
    __shared__ float sL[32];
    int ti = threadIdx.x;
    {
        int mi = ti & 31;                      // = qs*8 + h*4 + r
        int ngp = ti >> 5;                     // 0..7
        int qs = mi >> 3, h = (mi >> 2) & 1, r = mi & 3;
        int ml = mlbase + qs * 4 + h * 16 + r;
        const float* base = Lpart + ((size_t)(combo * 32 + ngp * 4)) * 256 + ml;
        sLp[mi][ngp] = (base[0] + base[256]) + (base[512] + base[768]);
    }
    __syncthreads();
    if (ti < 32) {
        float s = 0.f;
#pragma unroll
        for (int k = 0; k < 8; k++) s += sLp[ti][k];
        sL[ti] = s;
    }
    __syncthreads();
    size_t flat0 = (size_t)b * (NN * HIDD) + (size_t)(t & 255) * 2048 + (size_t)ti * 8;
    int lane = ti & 63;
    int qs = lane >> 4;
    u16b* gp = gB + flat0;
    s8v g = *reinterpret_cast<const s8v*>(gp);
    s8v o;
#pragma unroll
    for (int j = 0; j < 8; j++) {
        int mi = qs * 8 + ((j >> 2) << 2) + (j & 3);
        float v = b2f((unsigned short)g[j]) / sL[mi];
        o[j] = (short)f2b(v);
    }
    *reinterpret_cast<s8v*>(gp) = o;
}

// ---------- big path Phase 3: partial[ms] = P-slice @ G' (NO atomics) -----------
__global__ __launch_bounds__(256, 4) void pv_kernel(
    const u16b* __restrict__ P, const u16b* __restrict__ gB, u16b* __restrict__ pvPart)
{
    int xcd = blockIdx.x & 7;                  // grid 1024
    int inner = blockIdx.x >> 3;               // 0..127
    int combo = xcd * 2 + (inner & 1);         // 0..15 = b*4+ms (XCD-pinned)
    int b = combo >> 2;
    int ms = combo & 3;                        // 4-way m-split
    int ng = inner >> 1;                       // 0..63
    int w = threadIdx.x >> 6;
    int lane = threadIdx.x & 63;
    int l15 = lane & 15, q = lane >> 4;
    int ntile = ng * 4 + w;                    // 0..255, one ntile per wave

    const u16b* Pb = P + (size_t)b * NN * NN;
    const u16b* gp = gB + (size_t)b * (NN * HIDD);

    f4v acc[8];
#pragma unroll
    for (int i = 0; i < 8; i++) acc[i] = (f4v){0.f, 0.f, 0.f, 0.f};

    int ph = ng & 31;                          // stagger phase
    int k0 = ms * 32 + ph;
    int k1 = ms * 32 + ((ph + 1) & 31);
    s8v pcur = *reinterpret_cast<const s8v*>(Pb + ((size_t)(k0 * 256 + ntile) * 64 + lane) * 8);
    s8v pnx1 = *reinterpret_cast<const s8v*>(Pb + ((size_t)(k1 * 256 + ntile) * 64 + lane) * 8);

    for (int it = 0; it < 32; it++) {
        int kb2  = ms * 32 + ((it + ph) & 31);
        int kb2n = ms * 32 + ((it + 2 + ph) & 31);
        s8v pnx2 = *reinterpret_cast<const s8v*>(Pb + ((size_t)(kb2n * 256 + ntile) * 64 + lane) * 8);
#pragma unroll
        for (int ot = 0; ot < 8; ot++) {
            s8v gf = *reinterpret_cast<const s8v*>(gp + ((kb2 * 8 + ot) * 64 + lane) * 8);
            acc[ot] = __builtin_amdgcn_mfma_f32_16x16x32_bf16(pcur, gf, acc[ot], 0, 0, 0);
        }
        pcur = pnx1;
        pnx1 = pnx2;
    }

    u16b* pp = pvPart + (size_t)ms * ((size_t)BB * NN * HIDD) + (size_t)b * (NN * HIDD);
    int n_base = ntile * 16;
#pragma unroll
    for (int ot = 0; ot < 8; ot++) {
#pragma unroll
        for (int r = 0; r < 4; r++) {
            int n = n_base + q * 4 + r;
            int o = ot * 16 + l15;
            pp[swz(o, n, NN / 16)] = f2b(acc[ot][r]);
        }
    }
}

// ---------- big path Phase 4: y = x + w_mask @ (sum of partials)^T --------------
__global__ __launch_bounds__(256) void final_big_kernel(
    const float* __restrict__ x, const u16b* __restrict__ wmB,
    const u16b* __restrict__ pvPart, float* __restrict__ y)
{
    int wave = blockIdx.x * 4 + (threadIdx.x >> 6);   // 4096 waves
    int lane = threadIdx.x & 63;
    int l15 = lane & 15, q = lane >> 4;
    int b = wave >> 10;
    int rem = wave & 1023;
    int ctile = rem >> 6;
    int n64 = rem & 63;
    const size_t pstride = (size_t)BB * NN * HIDD;
    const u16b* pb = pvPart + (size_t)b * (NN * HIDD);
    const float* xb = x + (size_t)b * CC * NN;
    float* yb = y + (size_t)b * CC * NN;
    int c0 = ctile * 16;

    s8v aB[4];
#pragma unroll
    for (int kb = 0; kb < 4; kb++)
        aB[kb] = *reinterpret_cast<const s8v*>(wmB + (c0 + l15) * HIDD + kb * 32 + q * 8);

#pragma unroll
    for (int nt = 0; nt < 4; nt++) {
        int ntile = n64 * 4 + nt;
        f4v acc = (f4v){0.f, 0.f, 0.f, 0.f};
#pragma unroll
        for (int kb = 0; kb < 4; kb++) {
            size_t fo = ((size_t)(kb * 256 + ntile) * 64 + lane) * 8;
            float s[8];
#pragma unroll
            for (int j = 0; j < 8; j++) s[j] = 0.f;
#pragma unroll
            for (int p = 0; p < 4; p++) {
                s8v v = *reinterpret_cast<const s8v*>(pb + p * pstride + fo);
#pragma unroll
                for (int j = 0; j < 8; j++) s[j] += b2f((unsigned short)v[j]);
            }
            s8v bv;
#pragma unroll
            for (int j = 0; j < 8; j++) bv[j] = (short)f2b(s[j]);
            acc = __builtin_amdgcn_mfma_f32_16x16x32_bf16(aB[kb], bv, acc, 0, 0, 0);
        }
#pragma unroll
        for (int r = 0; r < 4; r++) {
            int c = c0 + q * 4 + r;
            int n = ntile * 16 + l15;
            size_t idx = (size_t)c * NN + n;
            yb[idx] = xb[idx] + acc[r];
        }
    }
}

// ---------- small path Phase 4: y = x + w_mask @ Out^T --------------------------
__global__ __launch_bounds__(256) void final_kernel(
    const float* __restrict__ x, const u16b* __restrict__ wmB,
    const float* __restrict__ outAcc, float* __restrict__ y)
{
    int wave = blockIdx.x * 4 + (threadIdx.x >> 6);   // 4096 waves
    int lane = threadIdx.x & 63;
    int l15 = lane & 15, q = lane >> 4;
    int b = wave >> 10;
    int rem = wave & 1023;
    int ctile = rem >> 6;
    int n64 = rem & 63;
    const float* oa = outAcc + (size_t)b * (NN * HIDD);
    const float* xb = x + (size_t)b * CC * NN;
    float* yb = y + (size_t)b * CC * NN;
    int c0 = ctile * 16;

    s8v aB[4];
#pragma unroll
    for (int kb = 0; kb < 4; kb++)
        aB[kb] = *reinterpret_cast<const s8v*>(wmB + (c0 + l15) * HIDD + kb * 32 + q * 8);

#pragma unroll
    for (int nt = 0; nt < 4; nt++) {
        int ntile = n64 * 4 + nt;
        f4v acc = (f4v){0.f, 0.f, 0.f, 0.f};
#pragma unroll
        for (int kb = 0; kb < 4; kb++) {
            const float* bp = oa + ((size_t)(kb * 256 + ntile) * 64 + lane) * 8;
            f4v b0 = *reinterpret_cast<const f4v*>(bp);
            f4v b1 = *reinterpret_cast<const f4v*>(bp + 4);
            s8v bv;
#pragma unroll
            for (int j = 0; j < 4; j++) {
                bv[j]     = (short)f2b(b0[j]);
                bv[j + 4] = (short)f2b(b1[j]);
            }
            acc = __builtin_amdgcn_mfma_f32_16x16x32_bf16(aB[kb], bv, acc, 0, 0, 0);
        }
#pragma unroll
        for (int r = 0; r < 4; r++) {
            int c = c0 + q * 4 + r;
            int n = ntile * 16 + l15;
            size_t idx = (size_t)c * NN + n;
            yb[idx] = xb[idx] + acc[r];
        }
    }
}

extern "C" void kernel_launch(void* const* d_in, const int* in_sizes, int n_in,
                              void* d_out, int out_size, void* d_ws, size_t ws_size,
                              hipStream_t stream)
{
    (void)in_sizes; (void)n_in; (void)out_size;
    const float* x  = (const float*)d_in[0];
    const float* wt = (const float*)d_in[1];
    const float* wp = (const float*)d_in[2];
    const float* wg = (const float*)d_in[3];
    const float* wm = (const float*)d_in[4];
    float* y = (float*)d_out;

    char* ws = (char*)d_ws;
    const size_t MB = 1 << 20;
    u16b* thetaF = (u16b*)(ws + 0 * MB);                   // 4 MB
    u16b* phiF   = (u16b*)(ws + 4 * MB);                   // 4 MB
    u16b* pvPart = (u16b*)(ws + 0 * MB);                   // 16 MB, overlays theta/phi (dead after spass)
    u16b* gB     = (u16b*)(ws + 16 * MB);                  // 4 MB
    float* outAcc = (float*)(ws + 20 * MB);                // 8 MB fp32 (small path)
    float* Lraw   = (float*)(ws + 28 * MB);                // 64 KB (small path)
    char* wbase = ws + 28 * MB + (64 << 10);
    u16b* wF  = (u16b*)(wbase);                            // 192 KB (theta+phi+g fp16)
    u16b* wmB = (u16b*)(wbase + (192 << 10));              // 64 KB
    float* Lpart = (float*)(ws + 30 * MB);                 // 2 MB (big path)
    u16b* P   = (u16b*)(ws + 32 * MB);                     // 134.2 MB (big path)

    const size_t need_big = 32 * MB + (size_t)BB * NN * NN * sizeof(u16b);
    const bool big = ws_size >= need_big;

    hipLaunchKernelGGL(prep_kernel, dim3(128), dim3(256), 0, stream,
                       wt, wp, wg, wm, wF, wmB);
    hipLaunchKernelGGL(proj_kernel, dim3(512), dim3(256), 0, stream,
                       x, wF, thetaF, phiF, gB);

    if (big) {
        hipLaunchKernelGGL(spass_kernel,    dim3(2048), dim3(256), 0, stream,
                           thetaF, phiF, P, Lpart);
        hipLaunchKernelGGL(lrescale_kernel, dim3(1024), dim3(256), 0, stream, gB, Lpart);
        // pv overwrites the theta/phi region (dead after spass) with bf16 partials
        hipLaunchKernelGGL(pv_kernel,       dim3(1024), dim3(256), 0, stream, P, gB, pvPart);
        hipLaunchKernelGGL(final_big_kernel, dim3(1024), dim3(256), 0, stream,
                           x, wmB, pvPart, y);
    } else {
        hipMemsetAsync(Lraw, 0, (size_t)BB * NN * sizeof(float), stream);
        hipMemsetAsync(outAcc, 0, (size_t)BB * NN * HIDD * sizeof(float), stream);
        hipLaunchKernelGGL(stats_kernel,   dim3(1024), dim3(256), 0, stream,
                           thetaF, phiF, Lraw);
        hipLaunchKernelGGL(rescale_kernel, dim3(1024), dim3(256), 0, stream, gB, Lraw);
        hipLaunchKernelGGL(attn_kernel,    dim3(1024), dim3(256), 0, stream,
                           thetaF, phiF, gB, outAcc);
        hipLaunchKernelGGL(final_kernel,   dim3(1024), dim3(256), 0, stream,
                           x, wmB, outAcc, y);
    }
}